// Round 32
// baseline (782.504 us; speedup 1.0000x reference)
//
#include <hip/hip_runtime.h>
#include <math.h>

#define B_EP 256
#define NT 175
#define NWAYS 20
#define KSHOT 5
#define NKS 100          // N_WAYS * N_SHOTS
#define NQ 75
#define DIM 512
#define NLAYERS 4
#define TAU_INV 10.0f
#define LOGIT_SCALE 5.0f
#define KNEI 5
#define SIMLD 176        // u16 stride for SIM-in-LDS (352B rows: conflict-free)
#define STLD2 72         // u16 stride for V k-chunk(64) staging; 144B, 16B-aligned
#define PALD 520         // u16 stride for Pa rows in LDS
#define NVB 700          // V gemm blocks (44800/64)

typedef unsigned int u32;
typedef unsigned short u16;
typedef __attribute__((ext_vector_type(8))) short s16x8;   // 8 bf16 in 4 VGPRs
typedef __attribute__((ext_vector_type(4))) float f32x4;

__device__ __forceinline__ float waveReduceSum(float v) {
#pragma unroll
  for (int off = 32; off >= 1; off >>= 1) v += __shfl_xor(v, off);
  return v;
}

__device__ __forceinline__ u32 pack2bf(float a, float b) {
  u32 ua = __float_as_uint(a), ub = __float_as_uint(b);
  ua = (ua + 0x7FFFu + ((ua >> 16) & 1u)) >> 16;
  ub = (ub + 0x7FFFu + ((ub >> 16) & 1u)) >> 16;
  return ua | (ub << 16);
}

__device__ __forceinline__ u16 pack1bf(float a) {
  u32 ua = __float_as_uint(a);
  return (u16)((ua + 0x7FFFu + ((ua >> 16) & 1u)) >> 16);
}

__device__ __forceinline__ float bflo(u32 u) { return __uint_as_float(u << 16); }
__device__ __forceinline__ float bfhi(u32 u) { return __uint_as_float(u & 0xFFFF0000u); }
__device__ __forceinline__ float bf1(u16 h) { return __uint_as_float((u32)h << 16); }

__device__ __forceinline__ float tanh_fast(float x) {
  float e = __expf(2.f * x);
  return 1.f - 2.f * __builtin_amdgcn_rcpf(e + 1.f);
}

__device__ __forceinline__ s16x8 ldfrag(const u16* p) {
  return __builtin_bit_cast(s16x8, *(const uint4*)p);
}

// async global->LDS, 16B per lane. LDS dest = wave-uniform base + lane*16.
__device__ __forceinline__ void gload16(const u16* g, u16* l) {
  __builtin_amdgcn_global_load_lds(
      (const __attribute__((address_space(1))) void*)g,
      (__attribute__((address_space(3))) void*)l, 16, 0, 0);
}

__global__ void init_accum_kernel(float* acc) {
  if (threadIdx.x < 16) acc[threadIdx.x] = 0.f;
}

// f32 -> bf16 (RNE), 8 elems/thread; both weight tensors in one launch.
__global__ void cvt_bf16_kernel(const float* __restrict__ in1,
                                const float* __restrict__ in2,
                                u16* __restrict__ outb, int n8_each) {
  const int nb1 = (n8_each + 255) / 256;
  int bid = blockIdx.x;
  const float* in = (bid < nb1) ? in1 : in2;
  u16* out = (bid < nb1) ? outb : outb + (size_t)n8_each * 8;
  if (bid >= nb1) bid -= nb1;
  int t = bid * 256 + threadIdx.x;
  if (t >= n8_each) return;
  const float4* p = (const float4*)(in + (size_t)t * 8);
  float4 a = p[0], b = p[1];
  uint4 r;
  r.x = pack2bf(a.x, a.y);
  r.y = pack2bf(a.z, a.w);
  r.z = pack2bf(b.x, b.y);
  r.w = pack2bf(b.z, b.w);
  *(uint4*)(out + (size_t)t * 8) = r;
}

// l2-normalize rows (512 wide) from f32 input -> bf16 master + bf16 residual.
__global__ void l2n_init_kernel(const float* __restrict__ in,
                                u16* __restrict__ outb,
                                u16* __restrict__ out0b) {
  const size_t row = blockIdx.x;
  const int lane = threadIdx.x;
  const float* src = in + row * DIM;
  float4 a = *(const float4*)(src + 4 * lane);
  float4 b = *(const float4*)(src + 256 + 4 * lane);
  float ss = a.x * a.x + a.y * a.y + a.z * a.z + a.w * a.w +
             b.x * b.x + b.y * b.y + b.z * b.z + b.w * b.w;
  ss = waveReduceSum(ss);
  const float inv = 1.f / fmaxf(sqrtf(ss), 1e-12f);
  a.x *= inv; a.y *= inv; a.z *= inv; a.w *= inv;
  b.x *= inv; b.y *= inv; b.z *= inv; b.w *= inv;
  uint2 pa, pb;
  pa.x = pack2bf(a.x, a.y); pa.y = pack2bf(a.z, a.w);
  pb.x = pack2bf(b.x, b.y); pb.y = pack2bf(b.z, b.w);
  *(uint2*)(outb + row * DIM + 4 * lane) = pa;
  *(uint2*)(outb + row * DIM + 256 + 4 * lane) = pb;
  *(uint2*)(out0b + row * DIM + 4 * lane) = pa;
  *(uint2*)(out0b + row * DIM + 256 + 4 * lane) = pb;
}

// Merged graph front-end: blocks [0,768) = instance sim/topk/msg (3 per
// episode); blocks [768,1024) = prototype branch (1 per episode, 256 thr).
__global__ __launch_bounds__(256) void graph_front_kernel(
    const u16* __restrict__ VB, const u16* __restrict__ PB,
    u16* __restrict__ MSGB, u16* __restrict__ PMSGB) {
  const int p = blockIdx.x;
  const int tid = threadIdx.x;
  const int wave = tid >> 6, lane = tid & 63;
  __shared__ __align__(16) u16 smem[25088];  // 50,176 B (sim: SIMs+Vst; p: Pl)
  __shared__ float Gl2[NWAYS][NWAYS];
  __shared__ float Wl2[NWAYS][KNEI];
  __shared__ int Il2[NWAYS][KNEI];
  if (p < 3 * B_EP) {
    // ---------------- instance-graph path ----------------
    const int b = p & 255, sl = p >> 8;  // 0..2
    u16* SIMs = smem;                 // 64*SIMLD u16
    u16* Vst = smem + 64 * SIMLD;     // 192*STLD2 u16
    const u16* Vb = VB + (size_t)b * NT * DIM;
    for (int i = tid; i < (192 - NT) * STLD2; i += 256)
      Vst[NT * STLD2 + i] = 0;
    f32x4 acc[4][4];
#pragma unroll
    for (int m = 0; m < 4; ++m)
#pragma unroll
      for (int n = 0; n < 4; ++n) acc[m][n] = (f32x4){0.f, 0.f, 0.f, 0.f};
    const int part = lane >> 4;  // 0..3
    for (int kk = 0; kk < DIM; kk += 64) {
      __syncthreads();
#pragma unroll
      for (int r6 = 0; r6 < 6; ++r6) {
        const int idx = tid + 256 * r6;
        if (idx < NT * 8) {
          const int row = idx >> 3, pp = idx & 7;
          uint4 v = *(const uint4*)(Vb + (size_t)row * DIM + kk + pp * 8);
          *(uint4*)&Vst[row * STLD2 + pp * 8] = v;
        }
      }
      __syncthreads();
      if (wave < 3) {
#pragma unroll
        for (int ks = 0; ks < 2; ++ks) {
          s16x8 fa[4], fb[4];
#pragma unroll
          for (int m = 0; m < 4; ++m)
            fa[m] = ldfrag(&Vst[(sl * 64 + m * 16 + (lane & 15)) * STLD2 +
                                ks * 32 + part * 8]);
#pragma unroll
          for (int n = 0; n < 4; ++n)
            fb[n] = ldfrag(&Vst[(wave * 64 + n * 16 + (lane & 15)) * STLD2 +
                                ks * 32 + part * 8]);
#pragma unroll
          for (int m = 0; m < 4; ++m)
#pragma unroll
            for (int n = 0; n < 4; ++n)
              acc[m][n] = __builtin_amdgcn_mfma_f32_16x16x32_bf16(
                  fa[m], fb[n], acc[m][n], 0, 0, 0);
        }
      }
    }
    const int r_ = (lane >> 4) * 4, c_ = lane & 15;
    if (wave < 3) {
#pragma unroll
      for (int m = 0; m < 4; ++m)
#pragma unroll
        for (int n = 0; n < 4; ++n)
#pragma unroll
          for (int j = 0; j < 4; ++j) {
            const int rl = m * 16 + r_ + j;          // 0..63 in slice
            const int c = wave * 64 + n * 16 + c_;   // 0..191
            if (sl * 64 + rl < NT && c < NT)
              SIMs[rl * SIMLD + c] = pack1bf(acc[m][n][j]);
          }
    }
    __syncthreads();
    for (int rl = wave; rl < 64; rl += 4) {
      const int rg = sl * 64 + rl;
      if (rg >= NT) break;
      u32 pk[3];
#pragma unroll
      for (int t = 0; t < 3; ++t) {
        int j = lane + 64 * t;
        if (j < NT) {
          u32 v = SIMs[rl * SIMLD + j];
          u32 key = v ^ ((v >> 15) ? 0xFFFFu : 0x8000u);
          pk[t] = (key << 8) | (u32)(255 - j);
        } else {
          pk[t] = 0u;
        }
      }
      float topv[KNEI];
      int topi[KNEI];
#pragma unroll
      for (int t = 0; t < KNEI; ++t) {
        u32 c = max(pk[0], max(pk[1], pk[2]));
#pragma unroll
        for (int off = 32; off >= 1; off >>= 1)
          c = max(c, (u32)__shfl_xor((int)c, off));
#pragma unroll
        for (int u = 0; u < 3; ++u)
          if (pk[u] == c) pk[u] = 0u;
        const u32 k16 = (c >> 8) & 0xFFFFu;
        const u32 v16 = (k16 & 0x8000u) ? (k16 ^ 0x8000u) : (~k16 & 0xFFFFu);
        topv[t] = bf1((u16)v16);
        topi[t] = 255 - (int)(c & 0xFFu);
      }
      float w[KNEI];
      float wsum = 0.f;
#pragma unroll
      for (int t = 0; t < KNEI; ++t) {
        w[t] = __expf((topv[t] - topv[0]) * TAU_INV);
        wsum += w[t];
      }
      const float invs = 1.f / wsum;
      float a8[8] = {0.f, 0.f, 0.f, 0.f, 0.f, 0.f, 0.f, 0.f};
#pragma unroll
      for (int t = 0; t < KNEI; ++t) {
        uint4 v = *(const uint4*)(Vb + (size_t)topi[t] * DIM + 8 * lane);
        a8[0] += w[t] * bflo(v.x); a8[1] += w[t] * bfhi(v.x);
        a8[2] += w[t] * bflo(v.y); a8[3] += w[t] * bfhi(v.y);
        a8[4] += w[t] * bflo(v.z); a8[5] += w[t] * bfhi(v.z);
        a8[6] += w[t] * bflo(v.w); a8[7] += w[t] * bfhi(v.w);
      }
      uint4 r;
      r.x = pack2bf(a8[0] * invs, a8[1] * invs);
      r.y = pack2bf(a8[2] * invs, a8[3] * invs);
      r.z = pack2bf(a8[4] * invs, a8[5] * invs);
      r.w = pack2bf(a8[6] * invs, a8[7] * invs);
      *(uint4*)(MSGB + ((size_t)b * NT + rg) * DIM + 8 * lane) = r;
    }
  } else {
    // ---------------- prototype-branch path ----------------
    const int b = p - 3 * B_EP;
    u16* Pl = smem;  // 32 rows x PALD u16
    const u16* Pb = PB + (size_t)b * NWAYS * DIM;
    for (int c = tid; c < 32 * 64; c += 256) {
      int m = c >> 6, ko = (c & 63) * 8;
      uint4 v = {0, 0, 0, 0};
      if (m < NWAYS) v = *(const uint4*)(Pb + (size_t)m * DIM + ko);
      *(uint4*)&Pl[m * PALD + ko] = v;
    }
    __syncthreads();
    if (wave == 0) {
      f32x4 acc[2][2];
#pragma unroll
      for (int m = 0; m < 2; ++m)
#pragma unroll
        for (int n = 0; n < 2; ++n) acc[m][n] = (f32x4){0.f, 0.f, 0.f, 0.f};
      for (int kk = 0; kk < DIM; kk += 32) {
        s16x8 f[2];
#pragma unroll
        for (int m = 0; m < 2; ++m)
          f[m] = ldfrag(&Pl[(m * 16 + (lane & 15)) * PALD + kk +
                            (lane >> 4) * 8]);
#pragma unroll
        for (int m = 0; m < 2; ++m)
#pragma unroll
          for (int n = 0; n < 2; ++n)
            acc[m][n] = __builtin_amdgcn_mfma_f32_16x16x32_bf16(
                f[m], f[n], acc[m][n], 0, 0, 0);
      }
      const int r_ = (lane >> 4) * 4, c_ = lane & 15;
#pragma unroll
      for (int m = 0; m < 2; ++m)
#pragma unroll
        for (int n = 0; n < 2; ++n)
#pragma unroll
          for (int j = 0; j < 4; ++j) {
            int r = m * 16 + r_ + j, c = n * 16 + c_;
            if (r < NWAYS && c < NWAYS) Gl2[r][c] = acc[m][n][j];
          }
    }
    __syncthreads();
    if (tid < NWAYS) {
      float sims[NWAYS];
#pragma unroll
      for (int m = 0; m < NWAYS; ++m) sims[m] = Gl2[tid][m];
      float topv[KNEI];
      int topi[KNEI];
#pragma unroll
      for (int t = 0; t < KNEI; ++t) {
        float bv = -INFINITY;
        int bi = 0;
#pragma unroll
        for (int m = 0; m < NWAYS; ++m)
          if (sims[m] > bv) { bv = sims[m]; bi = m; }
        sims[bi] = -INFINITY;
        topv[t] = bv;
        topi[t] = bi;
      }
      float w[KNEI], wsum = 0.f;
#pragma unroll
      for (int t = 0; t < KNEI; ++t) {
        w[t] = __expf((topv[t] - topv[0]) * TAU_INV);
        wsum += w[t];
      }
      const float invs = 1.f / wsum;
#pragma unroll
      for (int t = 0; t < KNEI; ++t) {
        Wl2[tid][t] = w[t] * invs;
        Il2[tid][t] = topi[t];
      }
    }
    __syncthreads();
    u16* outp = PMSGB + (size_t)b * NWAYS * DIM;
    for (int n = wave; n < NWAYS; n += 4) {
      float a8[8] = {0.f, 0.f, 0.f, 0.f, 0.f, 0.f, 0.f, 0.f};
#pragma unroll
      for (int t = 0; t < KNEI; ++t) {
        const float w = Wl2[n][t];
        uint4 v = *(const uint4*)&Pl[Il2[n][t] * PALD + 8 * lane];
        a8[0] += w * bflo(v.x); a8[1] += w * bfhi(v.x);
        a8[2] += w * bflo(v.y); a8[3] += w * bfhi(v.y);
        a8[4] += w * bflo(v.z); a8[5] += w * bfhi(v.z);
        a8[6] += w * bflo(v.w); a8[7] += w * bfhi(v.w);
      }
      uint4 r;
      r.x = pack2bf(a8[0], a8[1]);
      r.y = pack2bf(a8[2], a8[3]);
      r.z = pack2bf(a8[4], a8[5]);
      r.w = pack2bf(a8[6], a8[7]);
      *(uint4*)(outp + (size_t)n * DIM + 8 * lane) = r;
    }
  }
}

// Combined GNN layer tail for BOTH branches in one launch (780 blocks,
// 64 rows/block): blocks [0,700) = V rows, [700,780) = P rows.
__global__ __launch_bounds__(512) void gemm_fused_kernel(
    const u16* __restrict__ Av, const u16* __restrict__ Ap,
    const u16* __restrict__ Wv, const u16* __restrict__ Wp,
    const float* __restrict__ bias_v, const float* __restrict__ bias_p,
    const float* __restrict__ sv, const float* __restrict__ sp,
    u16* __restrict__ XBv, u16* __restrict__ XBp,
    const u16* __restrict__ X0v, const u16* __restrict__ X0p) {
  const int bid = blockIdx.x;
  const bool isV = bid < NVB;
  const int row0 = (isV ? bid : bid - NVB) * 64;
  const u16* A = isV ? Av : Ap;
  const u16* W = isV ? Wv : Wp;
  const float* bias = isV ? bias_v : bias_p;
  const float* scale_ptr = isV ? sv : sp;
  u16* XB = isV ? XBv : XBp;
  const u16* X0B = isV ? X0v : X0p;
  const int tid = threadIdx.x, wave = tid >> 6, lane = tid & 63;
  __shared__ __align__(16) u16 smem[18432];  // Bs 32KB + As 4KB; U reuses Bs
  u16* Bs = smem;           // 512x32 u16
  u16* As = smem + 16384;   // 64x32 u16
  f32x4 acc[4][4];
#pragma unroll
  for (int m = 0; m < 4; ++m)
#pragma unroll
    for (int n = 0; n < 4; ++n) acc[m][n] = (f32x4){0.f, 0.f, 0.f, 0.f};
  const int rsrc = lane >> 2;        // 0..15
  const int ksrc = (lane & 3) * 8;   // 0,8,16,24
  for (int kk = 0; kk < DIM; kk += 32) {
#pragma unroll
    for (int q = 0; q < 4; ++q) {
      const int t = wave * 4 + q;  // 0..31 covers all 512 W rows
      gload16(W + (size_t)(t * 16 + rsrc) * DIM + kk + ksrc, Bs + t * 512);
    }
    if (wave < 4)
      gload16(A + (size_t)(row0 + wave * 16 + rsrc) * DIM + kk + ksrc,
              As + wave * 512);
    __syncthreads();
    s16x8 fa[4], fb[4];
#pragma unroll
    for (int m = 0; m < 4; ++m)
      fa[m] = ldfrag(&As[(m * 16 + (lane & 15)) * 32 + (lane >> 4) * 8]);
#pragma unroll
    for (int n = 0; n < 4; ++n)
      fb[n] = ldfrag(
          &Bs[(wave * 64 + n * 16 + (lane & 15)) * 32 + (lane >> 4) * 8]);
#pragma unroll
    for (int m = 0; m < 4; ++m)
#pragma unroll
      for (int n = 0; n < 4; ++n)
        acc[m][n] = __builtin_amdgcn_mfma_f32_16x16x32_bf16(fa[m], fb[n],
                                                            acc[m][n], 0, 0, 0);
    __syncthreads();
  }
  const float s = *scale_ptr;
  const int rq = lane >> 4, c_ = lane & 15;
  const int prow = tid >> 4, sub = tid & 15;   // epilogue thread map (32 rows)
  const int rq2 = ((prow >> 2) & 3) << 1;
#pragma unroll
  for (int half = 0; half < 2; ++half) {
    __syncthreads();
#pragma unroll
    for (int n = 0; n < 4; ++n) {
      const int col = wave * 64 + n * 16 + c_;
      const float bc = bias[col];
      const int cbase = col >> 3, wof = col & 7;
#pragma unroll
      for (int mm = 0; mm < 2; ++mm) {
        const int m = half * 2 + mm;
#pragma unroll
        for (int j = 0; j < 4; ++j) {
          const int lr = mm * 16 + rq * 4 + j;  // local row 0..31
          const int cS = cbase ^ (((lr >> 2) & 3) << 1);
          smem[lr * 512 + cS * 8 + wof] =
              pack1bf(s * tanh_fast(acc[m][n][j] + bc));
        }
      }
    }
    __syncthreads();
    const int grow = row0 + half * 32 + prow;
    const u16* xrow = XB + (size_t)grow * DIM;
    const u16* x0row = X0B + (size_t)grow * DIM;
    float ss = 0.f;
#pragma unroll
    for (int i = 0; i < 4; ++i) {
      const int c = sub + 16 * i;
      uint4 xb = *(const uint4*)(xrow + c * 8);
      uint4 x0 = *(const uint4*)(x0row + c * 8);
      uint4 uu = *(const uint4*)&smem[prow * 512 + (c ^ rq2) * 8];
      float t0 = 0.8f * (bflo(xb.x) + bflo(uu.x)) + 0.2f * bflo(x0.x);
      float t1 = 0.8f * (bfhi(xb.x) + bfhi(uu.x)) + 0.2f * bfhi(x0.x);
      float t2 = 0.8f * (bflo(xb.y) + bflo(uu.y)) + 0.2f * bflo(x0.y);
      float t3 = 0.8f * (bfhi(xb.y) + bfhi(uu.y)) + 0.2f * bfhi(x0.y);
      float t4 = 0.8f * (bflo(xb.z) + bflo(uu.z)) + 0.2f * bflo(x0.z);
      float t5 = 0.8f * (bfhi(xb.z) + bfhi(uu.z)) + 0.2f * bfhi(x0.z);
      float t6 = 0.8f * (bflo(xb.w) + bflo(uu.w)) + 0.2f * bflo(x0.w);
      float t7 = 0.8f * (bfhi(xb.w) + bfhi(uu.w)) + 0.2f * bfhi(x0.w);
      ss += t0 * t0 + t1 * t1 + t2 * t2 + t3 * t3 + t4 * t4 + t5 * t5 +
            t6 * t6 + t7 * t7;
      uint4 tp;
      tp.x = pack2bf(t0, t1); tp.y = pack2bf(t2, t3);
      tp.z = pack2bf(t4, t5); tp.w = pack2bf(t6, t7);
      *(uint4*)&smem[prow * 512 + (c ^ rq2) * 8] = tp;
    }
#pragma unroll
    for (int off = 8; off >= 1; off >>= 1) ss += __shfl_xor(ss, off, 16);
    const float inv = 1.f / fmaxf(sqrtf(ss), 1e-12f);
    u16* orow = XB + (size_t)grow * DIM;
#pragma unroll
    for (int i = 0; i < 4; ++i) {
      const int c = sub + 16 * i;
      uint4 tp = *(const uint4*)&smem[prow * 512 + (c ^ rq2) * 8];
      uint4 r;
      r.x = pack2bf(bflo(tp.x) * inv, bfhi(tp.x) * inv);
      r.y = pack2bf(bflo(tp.y) * inv, bfhi(tp.y) * inv);
      r.z = pack2bf(bflo(tp.z) * inv, bfhi(tp.z) * inv);
      r.w = pack2bf(bflo(tp.w) * inv, bfhi(tp.w) * inv);
      *(uint4*)(orow + c * 8) = r;
    }
  }
}

// Merged guidance tail, 2 blocks per episode (grid 512), 1024 threads =
// 16 waves: with VGPR<=64 this gives 2 blocks/CU x 16 waves = full 32-wave
// occupancy. v8: step 1 strides 16 waves; step 2 = waves 0-5 SIMS (16 rows
// each) + wave 6 Gram; step 3 strides 16 waves over the 96-row slice.
__global__ __launch_bounds__(1024) void episode_post_kernel(
    const u16* __restrict__ VC, u16* __restrict__ VN,
    const u16* __restrict__ PB, const int* __restrict__ qy,
    const float* __restrict__ alpha_ptr, const float* __restrict__ beta_ptr,
    float* __restrict__ accum, int is_last) {
  const int p = blockIdx.x;
  const int b = p & 255, sl = p >> 8;  // 0..1
  const int tid = threadIdx.x, wave = tid >> 6, lane = tid & 63;
  __shared__ __align__(16) u16 palds[NWAYS * PALD];      // 20.8 KB
  __shared__ float SIMSl[96 * NWAYS];                    // 7.7 KB
  __shared__ float Gl[NWAYS][NWAYS + 1];                 // 1.7 KB
  __shared__ float red[32];
  const u16* Vb0 = VC + (size_t)b * NT * DIM;
  const float alpha = *alpha_ptr, oma = 1.f - alpha;
  const float beta = *beta_ptr, omb = 1.f - beta;
  const int row_lo = sl * 96;
  const int row_hi = (row_lo + 96 < NT) ? (row_lo + 96) : NT;
  // ---- step 1: Pa rows (vcpa) into palds (VC immutable -> deterministic) --
  for (int n = wave; n < NWAYS; n += 16) {
    const u16* base = Vb0 + (size_t)n * KSHOT * DIM;
    float a8[8] = {0.f, 0.f, 0.f, 0.f, 0.f, 0.f, 0.f, 0.f};
#pragma unroll
    for (int k = 0; k < KSHOT; ++k) {
      uint4 v = *(const uint4*)(base + (size_t)k * DIM + 8 * lane);
      a8[0] += bflo(v.x); a8[1] += bfhi(v.x);
      a8[2] += bflo(v.y); a8[3] += bfhi(v.y);
      a8[4] += bflo(v.z); a8[5] += bfhi(v.z);
      a8[6] += bflo(v.w); a8[7] += bfhi(v.w);
    }
    float ss = 0.f;
#pragma unroll
    for (int t = 0; t < 8; ++t) ss += a8[t] * a8[t];
    ss = waveReduceSum(ss);
    const float inv = 1.f / fmaxf(sqrtf(ss), 1e-12f);  // mean cancels in l2n
    {
      uint4 pp = *(const uint4*)(PB + ((size_t)b * NWAYS + n) * DIM + 8 * lane);
      a8[0] = alpha * bflo(pp.x) + oma * a8[0] * inv;
      a8[1] = alpha * bfhi(pp.x) + oma * a8[1] * inv;
      a8[2] = alpha * bflo(pp.y) + oma * a8[2] * inv;
      a8[3] = alpha * bfhi(pp.y) + oma * a8[3] * inv;
      a8[4] = alpha * bflo(pp.z) + oma * a8[4] * inv;
      a8[5] = alpha * bfhi(pp.z) + oma * a8[5] * inv;
      a8[6] = alpha * bflo(pp.w) + oma * a8[6] * inv;
      a8[7] = alpha * bfhi(pp.w) + oma * a8[7] * inv;
    }
    float s2 = 0.f;
#pragma unroll
    for (int t = 0; t < 8; ++t) s2 += a8[t] * a8[t];
    s2 = waveReduceSum(s2);
    const float inv2 = 1.f / fmaxf(sqrtf(s2), 1e-12f);
    uint4 r;
    r.x = pack2bf(a8[0] * inv2, a8[1] * inv2);
    r.y = pack2bf(a8[2] * inv2, a8[3] * inv2);
    r.z = pack2bf(a8[4] * inv2, a8[5] * inv2);
    r.w = pack2bf(a8[6] * inv2, a8[7] * inv2);
    *(uint4*)&palds[n * PALD + 8 * lane] = r;
  }
  __syncthreads();
  // ---- step 2: slice SIMS on waves 0-5 (16 rows each) + Gram on wave 6 ----
  const int part2 = lane >> 4, fr2 = lane & 15;
  if (wave < 6) {
    const int r0w = row_lo + wave * 16;
    f32x4 sacc[2];
    sacc[0] = (f32x4){0.f, 0.f, 0.f, 0.f};
    sacc[1] = (f32x4){0.f, 0.f, 0.f, 0.f};
    const int row = r0w + fr2;
    for (int kk = 0; kk < DIM; kk += 32) {
      s16x8 fa, fb[2];
      if (row < NT) {
        fa = __builtin_bit_cast(
            s16x8, *(const uint4*)(Vb0 + (size_t)row * DIM + kk + part2 * 8));
      } else {
        int pr = row - NT;
        if (pr > NWAYS - 1) pr = NWAYS - 1;
        fa = ldfrag(&palds[pr * PALD + kk + part2 * 8]);
      }
#pragma unroll
      for (int n = 0; n < 2; ++n)
        fb[n] = ldfrag(&palds[(n * 16 + fr2) * PALD + kk + part2 * 8]);
#pragma unroll
      for (int n = 0; n < 2; ++n)
        sacc[n] = __builtin_amdgcn_mfma_f32_16x16x32_bf16(fa, fb[n], sacc[n],
                                                          0, 0, 0);
    }
    const int r_ = (lane >> 4) * 4, c_ = lane & 15;
#pragma unroll
    for (int n = 0; n < 2; ++n)
#pragma unroll
      for (int j = 0; j < 4; ++j) {
        const int r = r0w + r_ + j, c = n * 16 + c_;
        if (c >= NWAYS) continue;
        if (r >= row_lo && r < row_hi)
          SIMSl[(r - row_lo) * NWAYS + c] = sacc[n][j];
        else if (r >= NT && r < NT + NWAYS)
          Gl[r - NT][c] = sacc[n][j];
      }
  } else if (wave == 6) {
    f32x4 sacc[2][2];
#pragma unroll
    for (int m = 0; m < 2; ++m)
#pragma unroll
      for (int n = 0; n < 2; ++n) sacc[m][n] = (f32x4){0.f, 0.f, 0.f, 0.f};
    for (int kk = 0; kk < DIM; kk += 32) {
      s16x8 fa[2], fb[2];
#pragma unroll
      for (int m = 0; m < 2; ++m) {
        int pr = m * 16 + fr2;
        if (pr > NWAYS - 1) pr = NWAYS - 1;
        fa[m] = ldfrag(&palds[pr * PALD + kk + part2 * 8]);
      }
#pragma unroll
      for (int n = 0; n < 2; ++n)
        fb[n] = ldfrag(&palds[(n * 16 + fr2) * PALD + kk + part2 * 8]);
#pragma unroll
      for (int m = 0; m < 2; ++m)
#pragma unroll
        for (int n = 0; n < 2; ++n)
          sacc[m][n] = __builtin_amdgcn_mfma_f32_16x16x32_bf16(
              fa[m], fb[n], sacc[m][n], 0, 0, 0);
    }
    const int r_ = (lane >> 4) * 4, c_ = lane & 15;
#pragma unroll
    for (int m = 0; m < 2; ++m)
#pragma unroll
      for (int n = 0; n < 2; ++n)
#pragma unroll
        for (int j = 0; j < 4; ++j) {
          const int r = m * 16 + r_ + j, c = n * 16 + c_;
          if (r < NWAYS && c < NWAYS) Gl[r][c] = sacc[m][n][j];
        }
  }
  __syncthreads();
  // ---- step 3: softmax + update (VC -> VN) + CE for query rows ----
  float ce_acc = 0.f, ac_acc = 0.f;
  if (!(is_last && sl == 0)) {
    const int rs = is_last ? ((row_lo > NKS ? row_lo : NKS) + wave)
                           : (row_lo + wave);
    for (int row = rs; row < row_hi; row += 16) {
      float s[NWAYS];
#pragma unroll
      for (int m = 0; m < NWAYS; ++m)
        s[m] = SIMSl[(row - row_lo) * NWAYS + m];  // broadcast
      float mx = s[0];
#pragma unroll
      for (int m = 1; m < NWAYS; ++m) mx = fmaxf(mx, s[m]);
      float e[NWAYS], wsum = 0.f, dN = 0.f;
#pragma unroll
      for (int m = 0; m < NWAYS; ++m) {
        e[m] = __expf((s[m] - mx) * TAU_INV);
        wsum += e[m];
        dN += e[m] * s[m];
      }
      const float cg = omb / wsum;
      const int ln = lane & 31;
      float sg = 0.f;
      if (ln < NWAYS) {
#pragma unroll
        for (int m = 0; m < NWAYS; ++m) sg += e[m] * Gl[m][ln];
      }
      float ege = (ln < NWAYS) ? e[ln] * sg : 0.f;
#pragma unroll
      for (int off = 16; off >= 1; off >>= 1) ege += __shfl_xor(ege, off, 32);
      const float nn2 = beta * beta + 2.f * beta * cg * dN + cg * cg * ege;
      const float inv = 1.f / fmaxf(sqrtf(nn2), 1e-12f);
      if (!is_last) {
        const u16* vrow = VC + ((size_t)b * NT + row) * DIM;
        uint4 v4 = *(const uint4*)(vrow + 8 * lane);
        float t0 = 0.f, t1 = 0.f, t2 = 0.f, t3 = 0.f;
        float t4 = 0.f, t5 = 0.f, t6 = 0.f, t7 = 0.f;
#pragma unroll
        for (int m = 0; m < NWAYS; ++m) {
          uint4 pp = *(const uint4*)&palds[m * PALD + 8 * lane];
          t0 += e[m] * bflo(pp.x); t1 += e[m] * bfhi(pp.x);
          t2 += e[m] * bflo(pp.y); t3 += e[m] * bfhi(pp.y);
          t4 += e[m] * bflo(pp.z); t5 += e[m] * bfhi(pp.z);
          t6 += e[m] * bflo(pp.w); t7 += e[m] * bfhi(pp.w);
        }
        uint4 r;
        r.x = pack2bf((beta * bflo(v4.x) + cg * t0) * inv,
                      (beta * bfhi(v4.x) + cg * t1) * inv);
        r.y = pack2bf((beta * bflo(v4.y) + cg * t2) * inv,
                      (beta * bfhi(v4.y) + cg * t3) * inv);
        r.z = pack2bf((beta * bflo(v4.z) + cg * t4) * inv,
                      (beta * bfhi(v4.z) + cg * t5) * inv);
        r.w = pack2bf((beta * bflo(v4.w) + cg * t6) * inv,
                      (beta * bfhi(v4.w) + cg * t7) * inv);
        *(uint4*)(VN + ((size_t)b * NT + row) * DIM + 8 * lane) = r;
      }
      if (row >= NKS) {
        float l = (ln < NWAYS)
                      ? LOGIT_SCALE * inv * (beta * s[ln] + cg * sg)
                      : -1e30f;
        float bv = l;
        int bi = ln;
#pragma unroll
        for (int off = 16; off >= 1; off >>= 1) {
          float ov = __shfl_xor(bv, off, 32);
          int oi = __shfl_xor(bi, off, 32);
          if (ov > bv || (ov == bv && oi < bi)) { bv = ov; bi = oi; }
        }
        float se = (ln < NWAYS) ? __expf(l - bv) : 0.f;
#pragma unroll
        for (int off = 16; off >= 1; off >>= 1) se += __shfl_xor(se, off, 32);
        const int yt = qy[b * NQ + (row - NKS)];
        const float ly = __shfl(l, yt, 32);
        if (lane == 0) {
          ce_acc += bv + __logf(se) - ly;
          ac_acc += (bi == yt) ? 1.f : 0.f;
        }
      }
    }
  }
  if (lane == 0) {
    red[wave] = ce_acc;
    red[16 + wave] = ac_acc;
  }
  __syncthreads();
  if (tid == 0 && sl == 1) {
    float ce = 0.f, ac = 0.f;
#pragma unroll
    for (int w8 = 0; w8 < 16; ++w8) {
      ce += red[w8];
      ac += red[16 + w8];
    }
    atomicAdd(&accum[0], ce);
    if (is_last) atomicAdd(&accum[1], ac);
  } else if (tid == 0 && sl == 0 && !is_last) {
    float ce = 0.f;
#pragma unroll
    for (int w8 = 0; w8 < 16; ++w8) ce += red[w8];
    atomicAdd(&accum[0], ce);
  }
}

__global__ void finalize_kernel(const float* __restrict__ acc,
                                float* __restrict__ out) {
  out[0] = acc[0] / (float)(NLAYERS * B_EP * NQ);
  out[1] = acc[1] / (float)(B_EP * NQ);
}

extern "C" void kernel_launch(void* const* d_in, const int* in_sizes, int n_in,
                              void* d_out, int out_size, void* d_ws,
                              size_t ws_size, hipStream_t stream) {
  const float* V_feat = (const float*)d_in[0];
  const float* P_feat = (const float*)d_in[1];
  const int* query_y = (const int*)d_in[2];
  const float* igb_W = (const float*)d_in[3];
  const float* igb_b = (const float*)d_in[4];
  const float* igb_s = (const float*)d_in[5];
  const float* pgb_W = (const float*)d_in[6];
  const float* pgb_b = (const float*)d_in[7];
  const float* pgb_s = (const float*)d_in[8];
  const float* alpha = (const float*)d_in[9];
  const float* beta = (const float*)d_in[10];
  float* out = (float*)d_out;

  float* ws = (float*)d_ws;
  const size_t vsz = (size_t)B_EP * NT * DIM;       // 22,937,600
  const size_t psz = (size_t)B_EP * NWAYS * DIM;    // 2,621,440
  const size_t wsz = (size_t)NLAYERS * DIM * DIM;   // 1,048,576
  float* ACC = ws;
  u16* VB = (u16*)(ws + 16);
  u16* V0B = VB + vsz;
  u16* MSGB = V0B + vsz;
  u16* PB = MSGB + vsz;
  u16* P0B = PB + psz;
  u16* PMSGB = P0B + psz;
  u16* WB = PMSGB + psz;
  u16* WPB = WB + wsz;

  init_accum_kernel<<<1, 64, 0, stream>>>(ACC);
  l2n_init_kernel<<<B_EP * NT, 64, 0, stream>>>(V_feat, VB, V0B);
  l2n_init_kernel<<<B_EP * NWAYS, 64, 0, stream>>>(P_feat, PB, P0B);
  {
    const int n8 = (int)(wsz / 8);
    const int nb1 = (n8 + 255) / 256;
    cvt_bf16_kernel<<<2 * nb1, 256, 0, stream>>>(igb_W, pgb_W, WB, n8);
  }

  for (int i = 0; i < NLAYERS; ++i) {
    u16* Vc = (i & 1) ? MSGB : VB;   // current V
    u16* Mn = (i & 1) ? VB : MSGB;   // message buffer, then V_next
    graph_front_kernel<<<4 * B_EP, 256, 0, stream>>>(Vc, PB, Mn, PMSGB);
    gemm_fused_kernel<<<NVB + B_EP * NWAYS / 64, 512, 0, stream>>>(
        Mn, PMSGB, WB + (size_t)i * DIM * DIM, WPB + (size_t)i * DIM * DIM,
        igb_b + (size_t)i * DIM, pgb_b + (size_t)i * DIM, igb_s + i, pgb_s + i,
        Vc, PB, V0B, P0B);
    episode_post_kernel<<<2 * B_EP, 1024, 0, stream>>>(
        Vc, Mn, PB, query_y, alpha, beta, ACC, (i == NLAYERS - 1) ? 1 : 0);
  }
  finalize_kernel<<<1, 1, 0, stream>>>(ACC, out);
}

// Round 33
// 772.803 us; speedup vs baseline: 1.0126x; 1.0126x over previous
//
#include <hip/hip_runtime.h>
#include <math.h>

#define B_EP 256
#define NT 175
#define NWAYS 20
#define KSHOT 5
#define NKS 100          // N_WAYS * N_SHOTS
#define NQ 75
#define DIM 512
#define NLAYERS 4
#define TAU_INV 10.0f
#define LOGIT_SCALE 5.0f
#define KNEI 5
#define SIMLD 176        // u16 stride for SIM-in-LDS (352B rows: conflict-free)
#define STLD2 72         // u16 stride for V k-chunk(64) staging; 144B, 16B-aligned
#define PALD 520         // u16 stride for Pa rows in LDS
#define NVB 700          // V gemm blocks (44800/64)

typedef unsigned int u32;
typedef unsigned short u16;
typedef __attribute__((ext_vector_type(8))) short s16x8;   // 8 bf16 in 4 VGPRs
typedef __attribute__((ext_vector_type(4))) float f32x4;

__device__ __forceinline__ float waveReduceSum(float v) {
#pragma unroll
  for (int off = 32; off >= 1; off >>= 1) v += __shfl_xor(v, off);
  return v;
}

__device__ __forceinline__ u32 pack2bf(float a, float b) {
  u32 ua = __float_as_uint(a), ub = __float_as_uint(b);
  ua = (ua + 0x7FFFu + ((ua >> 16) & 1u)) >> 16;
  ub = (ub + 0x7FFFu + ((ub >> 16) & 1u)) >> 16;
  return ua | (ub << 16);
}

__device__ __forceinline__ u16 pack1bf(float a) {
  u32 ua = __float_as_uint(a);
  return (u16)((ua + 0x7FFFu + ((ua >> 16) & 1u)) >> 16);
}

__device__ __forceinline__ float bflo(u32 u) { return __uint_as_float(u << 16); }
__device__ __forceinline__ float bfhi(u32 u) { return __uint_as_float(u & 0xFFFF0000u); }
__device__ __forceinline__ float bf1(u16 h) { return __uint_as_float((u32)h << 16); }

__device__ __forceinline__ float tanh_fast(float x) {
  float e = __expf(2.f * x);
  return 1.f - 2.f * __builtin_amdgcn_rcpf(e + 1.f);
}

__device__ __forceinline__ s16x8 ldfrag(const u16* p) {
  return __builtin_bit_cast(s16x8, *(const uint4*)p);
}

// async global->LDS, 16B per lane. LDS dest = wave-uniform base + lane*16.
__device__ __forceinline__ void gload16(const u16* g, u16* l) {
  __builtin_amdgcn_global_load_lds(
      (const __attribute__((address_space(1))) void*)g,
      (__attribute__((address_space(3))) void*)l, 16, 0, 0);
}

__global__ void init_accum_kernel(float* acc) {
  if (threadIdx.x < 16) acc[threadIdx.x] = 0.f;
}

// f32 -> bf16 (RNE), 8 elems/thread; both weight tensors in one launch.
__global__ void cvt_bf16_kernel(const float* __restrict__ in1,
                                const float* __restrict__ in2,
                                u16* __restrict__ outb, int n8_each) {
  const int nb1 = (n8_each + 255) / 256;
  int bid = blockIdx.x;
  const float* in = (bid < nb1) ? in1 : in2;
  u16* out = (bid < nb1) ? outb : outb + (size_t)n8_each * 8;
  if (bid >= nb1) bid -= nb1;
  int t = bid * 256 + threadIdx.x;
  if (t >= n8_each) return;
  const float4* p = (const float4*)(in + (size_t)t * 8);
  float4 a = p[0], b = p[1];
  uint4 r;
  r.x = pack2bf(a.x, a.y);
  r.y = pack2bf(a.z, a.w);
  r.z = pack2bf(b.x, b.y);
  r.w = pack2bf(b.z, b.w);
  *(uint4*)(out + (size_t)t * 8) = r;
}

// l2-normalize rows (512 wide) from f32 input -> bf16 master + bf16 residual.
__global__ void l2n_init_kernel(const float* __restrict__ in,
                                u16* __restrict__ outb,
                                u16* __restrict__ out0b) {
  const size_t row = blockIdx.x;
  const int lane = threadIdx.x;
  const float* src = in + row * DIM;
  float4 a = *(const float4*)(src + 4 * lane);
  float4 b = *(const float4*)(src + 256 + 4 * lane);
  float ss = a.x * a.x + a.y * a.y + a.z * a.z + a.w * a.w +
             b.x * b.x + b.y * b.y + b.z * b.z + b.w * b.w;
  ss = waveReduceSum(ss);
  const float inv = 1.f / fmaxf(sqrtf(ss), 1e-12f);
  a.x *= inv; a.y *= inv; a.z *= inv; a.w *= inv;
  b.x *= inv; b.y *= inv; b.z *= inv; b.w *= inv;
  uint2 pa, pb;
  pa.x = pack2bf(a.x, a.y); pa.y = pack2bf(a.z, a.w);
  pb.x = pack2bf(b.x, b.y); pb.y = pack2bf(b.z, b.w);
  *(uint2*)(outb + row * DIM + 4 * lane) = pa;
  *(uint2*)(outb + row * DIM + 256 + 4 * lane) = pb;
  *(uint2*)(out0b + row * DIM + 4 * lane) = pa;
  *(uint2*)(out0b + row * DIM + 256 + 4 * lane) = pb;
}

// Merged graph front-end: blocks [0,768) = instance sim/topk/msg (3 per
// episode); blocks [768,1024) = prototype branch (1 per episode, 256 thr).
__global__ __launch_bounds__(256) void graph_front_kernel(
    const u16* __restrict__ VB, const u16* __restrict__ PB,
    u16* __restrict__ MSGB, u16* __restrict__ PMSGB) {
  const int p = blockIdx.x;
  const int tid = threadIdx.x;
  const int wave = tid >> 6, lane = tid & 63;
  __shared__ __align__(16) u16 smem[25088];  // 50,176 B (sim: SIMs+Vst; p: Pl)
  __shared__ float Gl2[NWAYS][NWAYS];
  __shared__ float Wl2[NWAYS][KNEI];
  __shared__ int Il2[NWAYS][KNEI];
  if (p < 3 * B_EP) {
    // ---------------- instance-graph path ----------------
    const int b = p & 255, sl = p >> 8;  // 0..2
    u16* SIMs = smem;                 // 64*SIMLD u16
    u16* Vst = smem + 64 * SIMLD;     // 192*STLD2 u16
    const u16* Vb = VB + (size_t)b * NT * DIM;
    for (int i = tid; i < (192 - NT) * STLD2; i += 256)
      Vst[NT * STLD2 + i] = 0;
    f32x4 acc[4][4];
#pragma unroll
    for (int m = 0; m < 4; ++m)
#pragma unroll
      for (int n = 0; n < 4; ++n) acc[m][n] = (f32x4){0.f, 0.f, 0.f, 0.f};
    const int part = lane >> 4;  // 0..3
    for (int kk = 0; kk < DIM; kk += 64) {
      __syncthreads();
#pragma unroll
      for (int r6 = 0; r6 < 6; ++r6) {
        const int idx = tid + 256 * r6;
        if (idx < NT * 8) {
          const int row = idx >> 3, pp = idx & 7;
          uint4 v = *(const uint4*)(Vb + (size_t)row * DIM + kk + pp * 8);
          *(uint4*)&Vst[row * STLD2 + pp * 8] = v;
        }
      }
      __syncthreads();
      if (wave < 3) {
#pragma unroll
        for (int ks = 0; ks < 2; ++ks) {
          s16x8 fa[4], fb[4];
#pragma unroll
          for (int m = 0; m < 4; ++m)
            fa[m] = ldfrag(&Vst[(sl * 64 + m * 16 + (lane & 15)) * STLD2 +
                                ks * 32 + part * 8]);
#pragma unroll
          for (int n = 0; n < 4; ++n)
            fb[n] = ldfrag(&Vst[(wave * 64 + n * 16 + (lane & 15)) * STLD2 +
                                ks * 32 + part * 8]);
#pragma unroll
          for (int m = 0; m < 4; ++m)
#pragma unroll
            for (int n = 0; n < 4; ++n)
              acc[m][n] = __builtin_amdgcn_mfma_f32_16x16x32_bf16(
                  fa[m], fb[n], acc[m][n], 0, 0, 0);
        }
      }
    }
    const int r_ = (lane >> 4) * 4, c_ = lane & 15;
    if (wave < 3) {
#pragma unroll
      for (int m = 0; m < 4; ++m)
#pragma unroll
        for (int n = 0; n < 4; ++n)
#pragma unroll
          for (int j = 0; j < 4; ++j) {
            const int rl = m * 16 + r_ + j;          // 0..63 in slice
            const int c = wave * 64 + n * 16 + c_;   // 0..191
            if (sl * 64 + rl < NT && c < NT)
              SIMs[rl * SIMLD + c] = pack1bf(acc[m][n][j]);
          }
    }
    __syncthreads();
    for (int rl = wave; rl < 64; rl += 4) {
      const int rg = sl * 64 + rl;
      if (rg >= NT) break;
      u32 pk[3];
#pragma unroll
      for (int t = 0; t < 3; ++t) {
        int j = lane + 64 * t;
        if (j < NT) {
          u32 v = SIMs[rl * SIMLD + j];
          u32 key = v ^ ((v >> 15) ? 0xFFFFu : 0x8000u);
          pk[t] = (key << 8) | (u32)(255 - j);
        } else {
          pk[t] = 0u;
        }
      }
      float topv[KNEI];
      int topi[KNEI];
#pragma unroll
      for (int t = 0; t < KNEI; ++t) {
        u32 c = max(pk[0], max(pk[1], pk[2]));
#pragma unroll
        for (int off = 32; off >= 1; off >>= 1)
          c = max(c, (u32)__shfl_xor((int)c, off));
#pragma unroll
        for (int u = 0; u < 3; ++u)
          if (pk[u] == c) pk[u] = 0u;
        const u32 k16 = (c >> 8) & 0xFFFFu;
        const u32 v16 = (k16 & 0x8000u) ? (k16 ^ 0x8000u) : (~k16 & 0xFFFFu);
        topv[t] = bf1((u16)v16);
        topi[t] = 255 - (int)(c & 0xFFu);
      }
      float w[KNEI];
      float wsum = 0.f;
#pragma unroll
      for (int t = 0; t < KNEI; ++t) {
        w[t] = __expf((topv[t] - topv[0]) * TAU_INV);
        wsum += w[t];
      }
      const float invs = 1.f / wsum;
      float a8[8] = {0.f, 0.f, 0.f, 0.f, 0.f, 0.f, 0.f, 0.f};
#pragma unroll
      for (int t = 0; t < KNEI; ++t) {
        uint4 v = *(const uint4*)(Vb + (size_t)topi[t] * DIM + 8 * lane);
        a8[0] += w[t] * bflo(v.x); a8[1] += w[t] * bfhi(v.x);
        a8[2] += w[t] * bflo(v.y); a8[3] += w[t] * bfhi(v.y);
        a8[4] += w[t] * bflo(v.z); a8[5] += w[t] * bfhi(v.z);
        a8[6] += w[t] * bflo(v.w); a8[7] += w[t] * bfhi(v.w);
      }
      uint4 r;
      r.x = pack2bf(a8[0] * invs, a8[1] * invs);
      r.y = pack2bf(a8[2] * invs, a8[3] * invs);
      r.z = pack2bf(a8[4] * invs, a8[5] * invs);
      r.w = pack2bf(a8[6] * invs, a8[7] * invs);
      *(uint4*)(MSGB + ((size_t)b * NT + rg) * DIM + 8 * lane) = r;
    }
  } else {
    // ---------------- prototype-branch path ----------------
    const int b = p - 3 * B_EP;
    u16* Pl = smem;  // 32 rows x PALD u16
    const u16* Pb = PB + (size_t)b * NWAYS * DIM;
    for (int c = tid; c < 32 * 64; c += 256) {
      int m = c >> 6, ko = (c & 63) * 8;
      uint4 v = {0, 0, 0, 0};
      if (m < NWAYS) v = *(const uint4*)(Pb + (size_t)m * DIM + ko);
      *(uint4*)&Pl[m * PALD + ko] = v;
    }
    __syncthreads();
    if (wave == 0) {
      f32x4 acc[2][2];
#pragma unroll
      for (int m = 0; m < 2; ++m)
#pragma unroll
        for (int n = 0; n < 2; ++n) acc[m][n] = (f32x4){0.f, 0.f, 0.f, 0.f};
      for (int kk = 0; kk < DIM; kk += 32) {
        s16x8 f[2];
#pragma unroll
        for (int m = 0; m < 2; ++m)
          f[m] = ldfrag(&Pl[(m * 16 + (lane & 15)) * PALD + kk +
                            (lane >> 4) * 8]);
#pragma unroll
        for (int m = 0; m < 2; ++m)
#pragma unroll
          for (int n = 0; n < 2; ++n)
            acc[m][n] = __builtin_amdgcn_mfma_f32_16x16x32_bf16(
                f[m], f[n], acc[m][n], 0, 0, 0);
      }
      const int r_ = (lane >> 4) * 4, c_ = lane & 15;
#pragma unroll
      for (int m = 0; m < 2; ++m)
#pragma unroll
        for (int n = 0; n < 2; ++n)
#pragma unroll
          for (int j = 0; j < 4; ++j) {
            int r = m * 16 + r_ + j, c = n * 16 + c_;
            if (r < NWAYS && c < NWAYS) Gl2[r][c] = acc[m][n][j];
          }
    }
    __syncthreads();
    if (tid < NWAYS) {
      float sims[NWAYS];
#pragma unroll
      for (int m = 0; m < NWAYS; ++m) sims[m] = Gl2[tid][m];
      float topv[KNEI];
      int topi[KNEI];
#pragma unroll
      for (int t = 0; t < KNEI; ++t) {
        float bv = -INFINITY;
        int bi = 0;
#pragma unroll
        for (int m = 0; m < NWAYS; ++m)
          if (sims[m] > bv) { bv = sims[m]; bi = m; }
        sims[bi] = -INFINITY;
        topv[t] = bv;
        topi[t] = bi;
      }
      float w[KNEI], wsum = 0.f;
#pragma unroll
      for (int t = 0; t < KNEI; ++t) {
        w[t] = __expf((topv[t] - topv[0]) * TAU_INV);
        wsum += w[t];
      }
      const float invs = 1.f / wsum;
#pragma unroll
      for (int t = 0; t < KNEI; ++t) {
        Wl2[tid][t] = w[t] * invs;
        Il2[tid][t] = topi[t];
      }
    }
    __syncthreads();
    u16* outp = PMSGB + (size_t)b * NWAYS * DIM;
    for (int n = wave; n < NWAYS; n += 4) {
      float a8[8] = {0.f, 0.f, 0.f, 0.f, 0.f, 0.f, 0.f, 0.f};
#pragma unroll
      for (int t = 0; t < KNEI; ++t) {
        const float w = Wl2[n][t];
        uint4 v = *(const uint4*)&Pl[Il2[n][t] * PALD + 8 * lane];
        a8[0] += w * bflo(v.x); a8[1] += w * bfhi(v.x);
        a8[2] += w * bflo(v.y); a8[3] += w * bfhi(v.y);
        a8[4] += w * bflo(v.z); a8[5] += w * bfhi(v.z);
        a8[6] += w * bflo(v.w); a8[7] += w * bfhi(v.w);
      }
      uint4 r;
      r.x = pack2bf(a8[0], a8[1]);
      r.y = pack2bf(a8[2], a8[3]);
      r.z = pack2bf(a8[4], a8[5]);
      r.w = pack2bf(a8[6], a8[7]);
      *(uint4*)(outp + (size_t)n * DIM + 8 * lane) = r;
    }
  }
}

// Combined GNN layer tail for BOTH branches in one launch (780 blocks,
// 64 rows/block): blocks [0,700) = V rows, [700,780) = P rows.
__global__ __launch_bounds__(512) void gemm_fused_kernel(
    const u16* __restrict__ Av, const u16* __restrict__ Ap,
    const u16* __restrict__ Wv, const u16* __restrict__ Wp,
    const float* __restrict__ bias_v, const float* __restrict__ bias_p,
    const float* __restrict__ sv, const float* __restrict__ sp,
    u16* __restrict__ XBv, u16* __restrict__ XBp,
    const u16* __restrict__ X0v, const u16* __restrict__ X0p) {
  const int bid = blockIdx.x;
  const bool isV = bid < NVB;
  const int row0 = (isV ? bid : bid - NVB) * 64;
  const u16* A = isV ? Av : Ap;
  const u16* W = isV ? Wv : Wp;
  const float* bias = isV ? bias_v : bias_p;
  const float* scale_ptr = isV ? sv : sp;
  u16* XB = isV ? XBv : XBp;
  const u16* X0B = isV ? X0v : X0p;
  const int tid = threadIdx.x, wave = tid >> 6, lane = tid & 63;
  __shared__ __align__(16) u16 smem[18432];  // Bs 32KB + As 4KB; U reuses Bs
  u16* Bs = smem;           // 512x32 u16
  u16* As = smem + 16384;   // 64x32 u16
  f32x4 acc[4][4];
#pragma unroll
  for (int m = 0; m < 4; ++m)
#pragma unroll
    for (int n = 0; n < 4; ++n) acc[m][n] = (f32x4){0.f, 0.f, 0.f, 0.f};
  const int rsrc = lane >> 2;        // 0..15
  const int ksrc = (lane & 3) * 8;   // 0,8,16,24
  for (int kk = 0; kk < DIM; kk += 32) {
#pragma unroll
    for (int q = 0; q < 4; ++q) {
      const int t = wave * 4 + q;  // 0..31 covers all 512 W rows
      gload16(W + (size_t)(t * 16 + rsrc) * DIM + kk + ksrc, Bs + t * 512);
    }
    if (wave < 4)
      gload16(A + (size_t)(row0 + wave * 16 + rsrc) * DIM + kk + ksrc,
              As + wave * 512);
    __syncthreads();
    s16x8 fa[4], fb[4];
#pragma unroll
    for (int m = 0; m < 4; ++m)
      fa[m] = ldfrag(&As[(m * 16 + (lane & 15)) * 32 + (lane >> 4) * 8]);
#pragma unroll
    for (int n = 0; n < 4; ++n)
      fb[n] = ldfrag(
          &Bs[(wave * 64 + n * 16 + (lane & 15)) * 32 + (lane >> 4) * 8]);
#pragma unroll
    for (int m = 0; m < 4; ++m)
#pragma unroll
      for (int n = 0; n < 4; ++n)
        acc[m][n] = __builtin_amdgcn_mfma_f32_16x16x32_bf16(fa[m], fb[n],
                                                            acc[m][n], 0, 0, 0);
    __syncthreads();
  }
  const float s = *scale_ptr;
  const int rq = lane >> 4, c_ = lane & 15;
  const int prow = tid >> 4, sub = tid & 15;   // epilogue thread map (32 rows)
  const int rq2 = ((prow >> 2) & 3) << 1;
#pragma unroll
  for (int half = 0; half < 2; ++half) {
    __syncthreads();
#pragma unroll
    for (int n = 0; n < 4; ++n) {
      const int col = wave * 64 + n * 16 + c_;
      const float bc = bias[col];
      const int cbase = col >> 3, wof = col & 7;
#pragma unroll
      for (int mm = 0; mm < 2; ++mm) {
        const int m = half * 2 + mm;
#pragma unroll
        for (int j = 0; j < 4; ++j) {
          const int lr = mm * 16 + rq * 4 + j;  // local row 0..31
          const int cS = cbase ^ (((lr >> 2) & 3) << 1);
          smem[lr * 512 + cS * 8 + wof] =
              pack1bf(s * tanh_fast(acc[m][n][j] + bc));
        }
      }
    }
    __syncthreads();
    const int grow = row0 + half * 32 + prow;
    const u16* xrow = XB + (size_t)grow * DIM;
    const u16* x0row = X0B + (size_t)grow * DIM;
    float ss = 0.f;
#pragma unroll
    for (int i = 0; i < 4; ++i) {
      const int c = sub + 16 * i;
      uint4 xb = *(const uint4*)(xrow + c * 8);
      uint4 x0 = *(const uint4*)(x0row + c * 8);
      uint4 uu = *(const uint4*)&smem[prow * 512 + (c ^ rq2) * 8];
      float t0 = 0.8f * (bflo(xb.x) + bflo(uu.x)) + 0.2f * bflo(x0.x);
      float t1 = 0.8f * (bfhi(xb.x) + bfhi(uu.x)) + 0.2f * bfhi(x0.x);
      float t2 = 0.8f * (bflo(xb.y) + bflo(uu.y)) + 0.2f * bflo(x0.y);
      float t3 = 0.8f * (bfhi(xb.y) + bfhi(uu.y)) + 0.2f * bfhi(x0.y);
      float t4 = 0.8f * (bflo(xb.z) + bflo(uu.z)) + 0.2f * bflo(x0.z);
      float t5 = 0.8f * (bfhi(xb.z) + bfhi(uu.z)) + 0.2f * bfhi(x0.z);
      float t6 = 0.8f * (bflo(xb.w) + bflo(uu.w)) + 0.2f * bflo(x0.w);
      float t7 = 0.8f * (bfhi(xb.w) + bfhi(uu.w)) + 0.2f * bfhi(x0.w);
      ss += t0 * t0 + t1 * t1 + t2 * t2 + t3 * t3 + t4 * t4 + t5 * t5 +
            t6 * t6 + t7 * t7;
      uint4 tp;
      tp.x = pack2bf(t0, t1); tp.y = pack2bf(t2, t3);
      tp.z = pack2bf(t4, t5); tp.w = pack2bf(t6, t7);
      *(uint4*)&smem[prow * 512 + (c ^ rq2) * 8] = tp;
    }
#pragma unroll
    for (int off = 8; off >= 1; off >>= 1) ss += __shfl_xor(ss, off, 16);
    const float inv = 1.f / fmaxf(sqrtf(ss), 1e-12f);
    u16* orow = XB + (size_t)grow * DIM;
#pragma unroll
    for (int i = 0; i < 4; ++i) {
      const int c = sub + 16 * i;
      uint4 tp = *(const uint4*)&smem[prow * 512 + (c ^ rq2) * 8];
      uint4 r;
      r.x = pack2bf(bflo(tp.x) * inv, bfhi(tp.x) * inv);
      r.y = pack2bf(bflo(tp.y) * inv, bfhi(tp.y) * inv);
      r.z = pack2bf(bflo(tp.z) * inv, bfhi(tp.z) * inv);
      r.w = pack2bf(bflo(tp.w) * inv, bfhi(tp.w) * inv);
      *(uint4*)(orow + c * 8) = r;
    }
  }
}

// Merged guidance tail, 3 blocks per episode (grid 768 = 3 blocks/CU):
// sl = p>>8 picks a 64-row slice. v9: double-buffered V (reads VC immutable,
// writes VN) -- race-free for any split. Step 2: waves 0-3 own 16-row
// A-frags, wave 4 = Gram. Step 3 strides 8 waves over the 64-row slice.
__global__ __launch_bounds__(512) void episode_post_kernel(
    const u16* __restrict__ VC, u16* __restrict__ VN,
    const u16* __restrict__ PB, const int* __restrict__ qy,
    const float* __restrict__ alpha_ptr, const float* __restrict__ beta_ptr,
    float* __restrict__ accum, int is_last) {
  const int p = blockIdx.x;
  const int b = p & 255, sl = p >> 8;  // 0..2
  const int tid = threadIdx.x, wave = tid >> 6, lane = tid & 63;
  __shared__ __align__(16) u16 palds[NWAYS * PALD];      // 20.8 KB
  __shared__ float SIMSl[64 * NWAYS];                    // 5.1 KB
  __shared__ float Gl[NWAYS][NWAYS + 1];                 // 1.7 KB
  __shared__ float red[16];
  const u16* Vb0 = VC + (size_t)b * NT * DIM;
  const float alpha = *alpha_ptr, oma = 1.f - alpha;
  const float beta = *beta_ptr, omb = 1.f - beta;
  const int row_lo = sl * 64;
  const int row_hi = (row_lo + 64 < NT) ? (row_lo + 64) : NT;
  // ---- step 1: Pa rows (vcpa) into palds (VC immutable -> deterministic) --
  for (int n = wave; n < NWAYS; n += 8) {
    const u16* base = Vb0 + (size_t)n * KSHOT * DIM;
    float a8[8] = {0.f, 0.f, 0.f, 0.f, 0.f, 0.f, 0.f, 0.f};
#pragma unroll
    for (int k = 0; k < KSHOT; ++k) {
      uint4 v = *(const uint4*)(base + (size_t)k * DIM + 8 * lane);
      a8[0] += bflo(v.x); a8[1] += bfhi(v.x);
      a8[2] += bflo(v.y); a8[3] += bfhi(v.y);
      a8[4] += bflo(v.z); a8[5] += bfhi(v.z);
      a8[6] += bflo(v.w); a8[7] += bfhi(v.w);
    }
    float ss = 0.f;
#pragma unroll
    for (int t = 0; t < 8; ++t) ss += a8[t] * a8[t];
    ss = waveReduceSum(ss);
    const float inv = 1.f / fmaxf(sqrtf(ss), 1e-12f);  // mean cancels in l2n
    {
      uint4 pp = *(const uint4*)(PB + ((size_t)b * NWAYS + n) * DIM + 8 * lane);
      a8[0] = alpha * bflo(pp.x) + oma * a8[0] * inv;
      a8[1] = alpha * bfhi(pp.x) + oma * a8[1] * inv;
      a8[2] = alpha * bflo(pp.y) + oma * a8[2] * inv;
      a8[3] = alpha * bfhi(pp.y) + oma * a8[3] * inv;
      a8[4] = alpha * bflo(pp.z) + oma * a8[4] * inv;
      a8[5] = alpha * bfhi(pp.z) + oma * a8[5] * inv;
      a8[6] = alpha * bflo(pp.w) + oma * a8[6] * inv;
      a8[7] = alpha * bfhi(pp.w) + oma * a8[7] * inv;
    }
    float s2 = 0.f;
#pragma unroll
    for (int t = 0; t < 8; ++t) s2 += a8[t] * a8[t];
    s2 = waveReduceSum(s2);
    const float inv2 = 1.f / fmaxf(sqrtf(s2), 1e-12f);
    uint4 r;
    r.x = pack2bf(a8[0] * inv2, a8[1] * inv2);
    r.y = pack2bf(a8[2] * inv2, a8[3] * inv2);
    r.z = pack2bf(a8[4] * inv2, a8[5] * inv2);
    r.w = pack2bf(a8[6] * inv2, a8[7] * inv2);
    *(uint4*)&palds[n * PALD + 8 * lane] = r;
  }
  __syncthreads();
  // ---- step 2: slice SIMS on waves 0-3 (16 rows each) + Gram on wave 4 ----
  const int part2 = lane >> 4, fr2 = lane & 15;
  if (wave < 4) {
    const int r0w = row_lo + wave * 16;
    f32x4 sacc[2];
    sacc[0] = (f32x4){0.f, 0.f, 0.f, 0.f};
    sacc[1] = (f32x4){0.f, 0.f, 0.f, 0.f};
    const int row = r0w + fr2;
    for (int kk = 0; kk < DIM; kk += 32) {
      s16x8 fa, fb[2];
      if (row < NT) {
        fa = __builtin_bit_cast(
            s16x8, *(const uint4*)(Vb0 + (size_t)row * DIM + kk + part2 * 8));
      } else {
        int pr = row - NT;
        if (pr > NWAYS - 1) pr = NWAYS - 1;
        fa = ldfrag(&palds[pr * PALD + kk + part2 * 8]);
      }
#pragma unroll
      for (int n = 0; n < 2; ++n)
        fb[n] = ldfrag(&palds[(n * 16 + fr2) * PALD + kk + part2 * 8]);
#pragma unroll
      for (int n = 0; n < 2; ++n)
        sacc[n] = __builtin_amdgcn_mfma_f32_16x16x32_bf16(fa, fb[n], sacc[n],
                                                          0, 0, 0);
    }
    const int r_ = (lane >> 4) * 4, c_ = lane & 15;
#pragma unroll
    for (int n = 0; n < 2; ++n)
#pragma unroll
      for (int j = 0; j < 4; ++j) {
        const int r = r0w + r_ + j, c = n * 16 + c_;
        if (c >= NWAYS) continue;
        if (r >= row_lo && r < row_hi)
          SIMSl[(r - row_lo) * NWAYS + c] = sacc[n][j];
        else if (r >= NT && r < NT + NWAYS)
          Gl[r - NT][c] = sacc[n][j];
      }
  } else if (wave == 4) {
    f32x4 sacc[2][2];
#pragma unroll
    for (int m = 0; m < 2; ++m)
#pragma unroll
      for (int n = 0; n < 2; ++n) sacc[m][n] = (f32x4){0.f, 0.f, 0.f, 0.f};
    for (int kk = 0; kk < DIM; kk += 32) {
      s16x8 fa[2], fb[2];
#pragma unroll
      for (int m = 0; m < 2; ++m) {
        int pr = m * 16 + fr2;
        if (pr > NWAYS - 1) pr = NWAYS - 1;
        fa[m] = ldfrag(&palds[pr * PALD + kk + part2 * 8]);
      }
#pragma unroll
      for (int n = 0; n < 2; ++n)
        fb[n] = ldfrag(&palds[(n * 16 + fr2) * PALD + kk + part2 * 8]);
#pragma unroll
      for (int m = 0; m < 2; ++m)
#pragma unroll
        for (int n = 0; n < 2; ++n)
          sacc[m][n] = __builtin_amdgcn_mfma_f32_16x16x32_bf16(
              fa[m], fb[n], sacc[m][n], 0, 0, 0);
    }
    const int r_ = (lane >> 4) * 4, c_ = lane & 15;
#pragma unroll
    for (int m = 0; m < 2; ++m)
#pragma unroll
      for (int n = 0; n < 2; ++n)
#pragma unroll
        for (int j = 0; j < 4; ++j) {
          const int r = m * 16 + r_ + j, c = n * 16 + c_;
          if (r < NWAYS && c < NWAYS) Gl[r][c] = sacc[m][n][j];
        }
  }
  __syncthreads();
  // ---- step 3: softmax + update (VC -> VN) + CE for query rows ----
  float ce_acc = 0.f, ac_acc = 0.f;
  if (!(is_last && row_hi <= NKS)) {
    const int rs = is_last ? ((row_lo > NKS ? row_lo : NKS) + wave)
                           : (row_lo + wave);
    for (int row = rs; row < row_hi; row += 8) {
      float s[NWAYS];
#pragma unroll
      for (int m = 0; m < NWAYS; ++m)
        s[m] = SIMSl[(row - row_lo) * NWAYS + m];  // broadcast
      float mx = s[0];
#pragma unroll
      for (int m = 1; m < NWAYS; ++m) mx = fmaxf(mx, s[m]);
      float e[NWAYS], wsum = 0.f, dN = 0.f;
#pragma unroll
      for (int m = 0; m < NWAYS; ++m) {
        e[m] = __expf((s[m] - mx) * TAU_INV);
        wsum += e[m];
        dN += e[m] * s[m];
      }
      const float cg = omb / wsum;
      const int ln = lane & 31;
      float sg = 0.f;
      if (ln < NWAYS) {
#pragma unroll
        for (int m = 0; m < NWAYS; ++m) sg += e[m] * Gl[m][ln];
      }
      float ege = (ln < NWAYS) ? e[ln] * sg : 0.f;
#pragma unroll
      for (int off = 16; off >= 1; off >>= 1) ege += __shfl_xor(ege, off, 32);
      const float nn2 = beta * beta + 2.f * beta * cg * dN + cg * cg * ege;
      const float inv = 1.f / fmaxf(sqrtf(nn2), 1e-12f);
      if (!is_last) {
        const u16* vrow = VC + ((size_t)b * NT + row) * DIM;
        uint4 v4 = *(const uint4*)(vrow + 8 * lane);
        float t0 = 0.f, t1 = 0.f, t2 = 0.f, t3 = 0.f;
        float t4 = 0.f, t5 = 0.f, t6 = 0.f, t7 = 0.f;
#pragma unroll
        for (int m = 0; m < NWAYS; ++m) {
          uint4 pp = *(const uint4*)&palds[m * PALD + 8 * lane];
          t0 += e[m] * bflo(pp.x); t1 += e[m] * bfhi(pp.x);
          t2 += e[m] * bflo(pp.y); t3 += e[m] * bfhi(pp.y);
          t4 += e[m] * bflo(pp.z); t5 += e[m] * bfhi(pp.z);
          t6 += e[m] * bflo(pp.w); t7 += e[m] * bfhi(pp.w);
        }
        uint4 r;
        r.x = pack2bf((beta * bflo(v4.x) + cg * t0) * inv,
                      (beta * bfhi(v4.x) + cg * t1) * inv);
        r.y = pack2bf((beta * bflo(v4.y) + cg * t2) * inv,
                      (beta * bfhi(v4.y) + cg * t3) * inv);
        r.z = pack2bf((beta * bflo(v4.z) + cg * t4) * inv,
                      (beta * bfhi(v4.z) + cg * t5) * inv);
        r.w = pack2bf((beta * bflo(v4.w) + cg * t6) * inv,
                      (beta * bfhi(v4.w) + cg * t7) * inv);
        *(uint4*)(VN + ((size_t)b * NT + row) * DIM + 8 * lane) = r;
      }
      if (row >= NKS) {
        float l = (ln < NWAYS)
                      ? LOGIT_SCALE * inv * (beta * s[ln] + cg * sg)
                      : -1e30f;
        float bv = l;
        int bi = ln;
#pragma unroll
        for (int off = 16; off >= 1; off >>= 1) {
          float ov = __shfl_xor(bv, off, 32);
          int oi = __shfl_xor(bi, off, 32);
          if (ov > bv || (ov == bv && oi < bi)) { bv = ov; bi = oi; }
        }
        float se = (ln < NWAYS) ? __expf(l - bv) : 0.f;
#pragma unroll
        for (int off = 16; off >= 1; off >>= 1) se += __shfl_xor(se, off, 32);
        const int yt = qy[b * NQ + (row - NKS)];
        const float ly = __shfl(l, yt, 32);
        if (lane == 0) {
          ce_acc += bv + __logf(se) - ly;
          ac_acc += (bi == yt) ? 1.f : 0.f;
        }
      }
    }
  }
  if (lane == 0) {
    red[wave] = ce_acc;
    red[8 + wave] = ac_acc;
  }
  __syncthreads();
  if (tid == 0 && row_hi > NKS) {
    float ce = 0.f, ac = 0.f;
#pragma unroll
    for (int w8 = 0; w8 < 8; ++w8) {
      ce += red[w8];
      ac += red[8 + w8];
    }
    atomicAdd(&accum[0], ce);
    if (is_last) atomicAdd(&accum[1], ac);
  }
}

__global__ void finalize_kernel(const float* __restrict__ acc,
                                float* __restrict__ out) {
  out[0] = acc[0] / (float)(NLAYERS * B_EP * NQ);
  out[1] = acc[1] / (float)(B_EP * NQ);
}

extern "C" void kernel_launch(void* const* d_in, const int* in_sizes, int n_in,
                              void* d_out, int out_size, void* d_ws,
                              size_t ws_size, hipStream_t stream) {
  const float* V_feat = (const float*)d_in[0];
  const float* P_feat = (const float*)d_in[1];
  const int* query_y = (const int*)d_in[2];
  const float* igb_W = (const float*)d_in[3];
  const float* igb_b = (const float*)d_in[4];
  const float* igb_s = (const float*)d_in[5];
  const float* pgb_W = (const float*)d_in[6];
  const float* pgb_b = (const float*)d_in[7];
  const float* pgb_s = (const float*)d_in[8];
  const float* alpha = (const float*)d_in[9];
  const float* beta = (const float*)d_in[10];
  float* out = (float*)d_out;

  float* ws = (float*)d_ws;
  const size_t vsz = (size_t)B_EP * NT * DIM;       // 22,937,600
  const size_t psz = (size_t)B_EP * NWAYS * DIM;    // 2,621,440
  const size_t wsz = (size_t)NLAYERS * DIM * DIM;   // 1,048,576
  float* ACC = ws;
  u16* VB = (u16*)(ws + 16);
  u16* V0B = VB + vsz;
  u16* MSGB = V0B + vsz;
  u16* PB = MSGB + vsz;
  u16* P0B = PB + psz;
  u16* PMSGB = P0B + psz;
  u16* WB = PMSGB + psz;
  u16* WPB = WB + wsz;

  init_accum_kernel<<<1, 64, 0, stream>>>(ACC);
  l2n_init_kernel<<<B_EP * NT, 64, 0, stream>>>(V_feat, VB, V0B);
  l2n_init_kernel<<<B_EP * NWAYS, 64, 0, stream>>>(P_feat, PB, P0B);
  {
    const int n8 = (int)(wsz / 8);
    const int nb1 = (n8 + 255) / 256;
    cvt_bf16_kernel<<<2 * nb1, 256, 0, stream>>>(igb_W, pgb_W, WB, n8);
  }

  for (int i = 0; i < NLAYERS; ++i) {
    u16* Vc = (i & 1) ? MSGB : VB;   // current V
    u16* Mn = (i & 1) ? VB : MSGB;   // message buffer, then V_next
    graph_front_kernel<<<4 * B_EP, 256, 0, stream>>>(Vc, PB, Mn, PMSGB);
    gemm_fused_kernel<<<NVB + B_EP * NWAYS / 64, 512, 0, stream>>>(
        Mn, PMSGB, WB + (size_t)i * DIM * DIM, WPB + (size_t)i * DIM * DIM,
        igb_b + (size_t)i * DIM, pgb_b + (size_t)i * DIM, igb_s + i, pgb_s + i,
        Vc, PB, V0B, P0B);
    episode_post_kernel<<<3 * B_EP, 512, 0, stream>>>(
        Vc, Mn, PB, query_y, alpha, beta, ACC, (i == NLAYERS - 1) ? 1 : 0);
  }
  finalize_kernel<<<1, 1, 0, stream>>>(ACC, out);
}

// Round 34
// 766.280 us; speedup vs baseline: 1.0212x; 1.0085x over previous
//
#include <hip/hip_runtime.h>
#include <math.h>

#define B_EP 256
#define NT 175
#define NWAYS 20
#define KSHOT 5
#define NKS 100          // N_WAYS * N_SHOTS
#define NQ 75
#define DIM 512
#define NLAYERS 4
#define TAU_INV 10.0f
#define LOGIT_SCALE 5.0f
#define KNEI 5
#define SIMLD 176        // u16 stride for SIM-in-LDS (352B rows: conflict-free)
#define STLD2 72         // u16 stride for V k-chunk(64) staging; 144B, 16B-aligned
#define PALD 520         // u16 stride for Pa rows in LDS
#define NVB 700          // V gemm blocks (44800/64)

typedef unsigned int u32;
typedef unsigned short u16;
typedef __attribute__((ext_vector_type(8))) short s16x8;   // 8 bf16 in 4 VGPRs
typedef __attribute__((ext_vector_type(4))) float f32x4;

__device__ __forceinline__ float waveReduceSum(float v) {
#pragma unroll
  for (int off = 32; off >= 1; off >>= 1) v += __shfl_xor(v, off);
  return v;
}

__device__ __forceinline__ u32 pack2bf(float a, float b) {
  u32 ua = __float_as_uint(a), ub = __float_as_uint(b);
  ua = (ua + 0x7FFFu + ((ua >> 16) & 1u)) >> 16;
  ub = (ub + 0x7FFFu + ((ub >> 16) & 1u)) >> 16;
  return ua | (ub << 16);
}

__device__ __forceinline__ u16 pack1bf(float a) {
  u32 ua = __float_as_uint(a);
  return (u16)((ua + 0x7FFFu + ((ua >> 16) & 1u)) >> 16);
}

__device__ __forceinline__ float bflo(u32 u) { return __uint_as_float(u << 16); }
__device__ __forceinline__ float bfhi(u32 u) { return __uint_as_float(u & 0xFFFF0000u); }
__device__ __forceinline__ float bf1(u16 h) { return __uint_as_float((u32)h << 16); }

__device__ __forceinline__ float tanh_fast(float x) {
  float e = __expf(2.f * x);
  return 1.f - 2.f * __builtin_amdgcn_rcpf(e + 1.f);
}

__device__ __forceinline__ s16x8 ldfrag(const u16* p) {
  return __builtin_bit_cast(s16x8, *(const uint4*)p);
}

// async global->LDS, 16B per lane. LDS dest = wave-uniform base + lane*16.
__device__ __forceinline__ void gload16(const u16* g, u16* l) {
  __builtin_amdgcn_global_load_lds(
      (const __attribute__((address_space(1))) void*)g,
      (__attribute__((address_space(3))) void*)l, 16, 0, 0);
}

__global__ void init_accum_kernel(float* acc) {
  if (threadIdx.x < 16) acc[threadIdx.x] = 0.f;
}

// f32 -> bf16 (RNE), 8 elems/thread; both weight tensors in one launch.
__global__ void cvt_bf16_kernel(const float* __restrict__ in1,
                                const float* __restrict__ in2,
                                u16* __restrict__ outb, int n8_each) {
  const int nb1 = (n8_each + 255) / 256;
  int bid = blockIdx.x;
  const float* in = (bid < nb1) ? in1 : in2;
  u16* out = (bid < nb1) ? outb : outb + (size_t)n8_each * 8;
  if (bid >= nb1) bid -= nb1;
  int t = bid * 256 + threadIdx.x;
  if (t >= n8_each) return;
  const float4* p = (const float4*)(in + (size_t)t * 8);
  float4 a = p[0], b = p[1];
  uint4 r;
  r.x = pack2bf(a.x, a.y);
  r.y = pack2bf(a.z, a.w);
  r.z = pack2bf(b.x, b.y);
  r.w = pack2bf(b.z, b.w);
  *(uint4*)(out + (size_t)t * 8) = r;
}

// l2-normalize rows (512 wide) from f32 input -> bf16 master + bf16 residual.
__global__ void l2n_init_kernel(const float* __restrict__ in,
                                u16* __restrict__ outb,
                                u16* __restrict__ out0b) {
  const size_t row = blockIdx.x;
  const int lane = threadIdx.x;
  const float* src = in + row * DIM;
  float4 a = *(const float4*)(src + 4 * lane);
  float4 b = *(const float4*)(src + 256 + 4 * lane);
  float ss = a.x * a.x + a.y * a.y + a.z * a.z + a.w * a.w +
             b.x * b.x + b.y * b.y + b.z * b.z + b.w * b.w;
  ss = waveReduceSum(ss);
  const float inv = 1.f / fmaxf(sqrtf(ss), 1e-12f);
  a.x *= inv; a.y *= inv; a.z *= inv; a.w *= inv;
  b.x *= inv; b.y *= inv; b.z *= inv; b.w *= inv;
  uint2 pa, pb;
  pa.x = pack2bf(a.x, a.y); pa.y = pack2bf(a.z, a.w);
  pb.x = pack2bf(b.x, b.y); pb.y = pack2bf(b.z, b.w);
  *(uint2*)(outb + row * DIM + 4 * lane) = pa;
  *(uint2*)(outb + row * DIM + 256 + 4 * lane) = pb;
  *(uint2*)(out0b + row * DIM + 4 * lane) = pa;
  *(uint2*)(out0b + row * DIM + 256 + 4 * lane) = pb;
}

// Merged graph front-end: blocks [0,768) = instance sim/topk/msg (3 per
// episode); blocks [768,1024) = prototype branch (1 per episode, 256 thr).
__global__ __launch_bounds__(256) void graph_front_kernel(
    const u16* __restrict__ VB, const u16* __restrict__ PB,
    u16* __restrict__ MSGB, u16* __restrict__ PMSGB) {
  const int p = blockIdx.x;
  const int tid = threadIdx.x;
  const int wave = tid >> 6, lane = tid & 63;
  __shared__ __align__(16) u16 smem[25088];  // 50,176 B (sim: SIMs+Vst; p: Pl)
  __shared__ float Gl2[NWAYS][NWAYS];
  __shared__ float Wl2[NWAYS][KNEI];
  __shared__ int Il2[NWAYS][KNEI];
  if (p < 3 * B_EP) {
    // ---------------- instance-graph path ----------------
    const int b = p & 255, sl = p >> 8;  // 0..2
    u16* SIMs = smem;                 // 64*SIMLD u16
    u16* Vst = smem + 64 * SIMLD;     // 192*STLD2 u16
    const u16* Vb = VB + (size_t)b * NT * DIM;
    for (int i = tid; i < (192 - NT) * STLD2; i += 256)
      Vst[NT * STLD2 + i] = 0;
    f32x4 acc[4][4];
#pragma unroll
    for (int m = 0; m < 4; ++m)
#pragma unroll
      for (int n = 0; n < 4; ++n) acc[m][n] = (f32x4){0.f, 0.f, 0.f, 0.f};
    const int part = lane >> 4;  // 0..3
    for (int kk = 0; kk < DIM; kk += 64) {
      __syncthreads();
#pragma unroll
      for (int r6 = 0; r6 < 6; ++r6) {
        const int idx = tid + 256 * r6;
        if (idx < NT * 8) {
          const int row = idx >> 3, pp = idx & 7;
          uint4 v = *(const uint4*)(Vb + (size_t)row * DIM + kk + pp * 8);
          *(uint4*)&Vst[row * STLD2 + pp * 8] = v;
        }
      }
      __syncthreads();
      if (wave < 3) {
#pragma unroll
        for (int ks = 0; ks < 2; ++ks) {
          s16x8 fa[4], fb[4];
#pragma unroll
          for (int m = 0; m < 4; ++m)
            fa[m] = ldfrag(&Vst[(sl * 64 + m * 16 + (lane & 15)) * STLD2 +
                                ks * 32 + part * 8]);
#pragma unroll
          for (int n = 0; n < 4; ++n)
            fb[n] = ldfrag(&Vst[(wave * 64 + n * 16 + (lane & 15)) * STLD2 +
                                ks * 32 + part * 8]);
#pragma unroll
          for (int m = 0; m < 4; ++m)
#pragma unroll
            for (int n = 0; n < 4; ++n)
              acc[m][n] = __builtin_amdgcn_mfma_f32_16x16x32_bf16(
                  fa[m], fb[n], acc[m][n], 0, 0, 0);
        }
      }
    }
    const int r_ = (lane >> 4) * 4, c_ = lane & 15;
    if (wave < 3) {
#pragma unroll
      for (int m = 0; m < 4; ++m)
#pragma unroll
        for (int n = 0; n < 4; ++n)
#pragma unroll
          for (int j = 0; j < 4; ++j) {
            const int rl = m * 16 + r_ + j;          // 0..63 in slice
            const int c = wave * 64 + n * 16 + c_;   // 0..191
            if (sl * 64 + rl < NT && c < NT)
              SIMs[rl * SIMLD + c] = pack1bf(acc[m][n][j]);
          }
    }
    __syncthreads();
    for (int rl = wave; rl < 64; rl += 4) {
      const int rg = sl * 64 + rl;
      if (rg >= NT) break;
      u32 pk[3];
#pragma unroll
      for (int t = 0; t < 3; ++t) {
        int j = lane + 64 * t;
        if (j < NT) {
          u32 v = SIMs[rl * SIMLD + j];
          u32 key = v ^ ((v >> 15) ? 0xFFFFu : 0x8000u);
          pk[t] = (key << 8) | (u32)(255 - j);
        } else {
          pk[t] = 0u;
        }
      }
      float topv[KNEI];
      int topi[KNEI];
#pragma unroll
      for (int t = 0; t < KNEI; ++t) {
        u32 c = max(pk[0], max(pk[1], pk[2]));
#pragma unroll
        for (int off = 32; off >= 1; off >>= 1)
          c = max(c, (u32)__shfl_xor((int)c, off));
#pragma unroll
        for (int u = 0; u < 3; ++u)
          if (pk[u] == c) pk[u] = 0u;
        const u32 k16 = (c >> 8) & 0xFFFFu;
        const u32 v16 = (k16 & 0x8000u) ? (k16 ^ 0x8000u) : (~k16 & 0xFFFFu);
        topv[t] = bf1((u16)v16);
        topi[t] = 255 - (int)(c & 0xFFu);
      }
      float w[KNEI];
      float wsum = 0.f;
#pragma unroll
      for (int t = 0; t < KNEI; ++t) {
        w[t] = __expf((topv[t] - topv[0]) * TAU_INV);
        wsum += w[t];
      }
      const float invs = 1.f / wsum;
      float a8[8] = {0.f, 0.f, 0.f, 0.f, 0.f, 0.f, 0.f, 0.f};
#pragma unroll
      for (int t = 0; t < KNEI; ++t) {
        uint4 v = *(const uint4*)(Vb + (size_t)topi[t] * DIM + 8 * lane);
        a8[0] += w[t] * bflo(v.x); a8[1] += w[t] * bfhi(v.x);
        a8[2] += w[t] * bflo(v.y); a8[3] += w[t] * bfhi(v.y);
        a8[4] += w[t] * bflo(v.z); a8[5] += w[t] * bfhi(v.z);
        a8[6] += w[t] * bflo(v.w); a8[7] += w[t] * bfhi(v.w);
      }
      uint4 r;
      r.x = pack2bf(a8[0] * invs, a8[1] * invs);
      r.y = pack2bf(a8[2] * invs, a8[3] * invs);
      r.z = pack2bf(a8[4] * invs, a8[5] * invs);
      r.w = pack2bf(a8[6] * invs, a8[7] * invs);
      *(uint4*)(MSGB + ((size_t)b * NT + rg) * DIM + 8 * lane) = r;
    }
  } else {
    // ---------------- prototype-branch path ----------------
    const int b = p - 3 * B_EP;
    u16* Pl = smem;  // 32 rows x PALD u16
    const u16* Pb = PB + (size_t)b * NWAYS * DIM;
    for (int c = tid; c < 32 * 64; c += 256) {
      int m = c >> 6, ko = (c & 63) * 8;
      uint4 v = {0, 0, 0, 0};
      if (m < NWAYS) v = *(const uint4*)(Pb + (size_t)m * DIM + ko);
      *(uint4*)&Pl[m * PALD + ko] = v;
    }
    __syncthreads();
    if (wave == 0) {
      f32x4 acc[2][2];
#pragma unroll
      for (int m = 0; m < 2; ++m)
#pragma unroll
        for (int n = 0; n < 2; ++n) acc[m][n] = (f32x4){0.f, 0.f, 0.f, 0.f};
      for (int kk = 0; kk < DIM; kk += 32) {
        s16x8 f[2];
#pragma unroll
        for (int m = 0; m < 2; ++m)
          f[m] = ldfrag(&Pl[(m * 16 + (lane & 15)) * PALD + kk +
                            (lane >> 4) * 8]);
#pragma unroll
        for (int m = 0; m < 2; ++m)
#pragma unroll
          for (int n = 0; n < 2; ++n)
            acc[m][n] = __builtin_amdgcn_mfma_f32_16x16x32_bf16(
                f[m], f[n], acc[m][n], 0, 0, 0);
      }
      const int r_ = (lane >> 4) * 4, c_ = lane & 15;
#pragma unroll
      for (int m = 0; m < 2; ++m)
#pragma unroll
        for (int n = 0; n < 2; ++n)
#pragma unroll
          for (int j = 0; j < 4; ++j) {
            int r = m * 16 + r_ + j, c = n * 16 + c_;
            if (r < NWAYS && c < NWAYS) Gl2[r][c] = acc[m][n][j];
          }
    }
    __syncthreads();
    if (tid < NWAYS) {
      float sims[NWAYS];
#pragma unroll
      for (int m = 0; m < NWAYS; ++m) sims[m] = Gl2[tid][m];
      float topv[KNEI];
      int topi[KNEI];
#pragma unroll
      for (int t = 0; t < KNEI; ++t) {
        float bv = -INFINITY;
        int bi = 0;
#pragma unroll
        for (int m = 0; m < NWAYS; ++m)
          if (sims[m] > bv) { bv = sims[m]; bi = m; }
        sims[bi] = -INFINITY;
        topv[t] = bv;
        topi[t] = bi;
      }
      float w[KNEI], wsum = 0.f;
#pragma unroll
      for (int t = 0; t < KNEI; ++t) {
        w[t] = __expf((topv[t] - topv[0]) * TAU_INV);
        wsum += w[t];
      }
      const float invs = 1.f / wsum;
#pragma unroll
      for (int t = 0; t < KNEI; ++t) {
        Wl2[tid][t] = w[t] * invs;
        Il2[tid][t] = topi[t];
      }
    }
    __syncthreads();
    u16* outp = PMSGB + (size_t)b * NWAYS * DIM;
    for (int n = wave; n < NWAYS; n += 4) {
      float a8[8] = {0.f, 0.f, 0.f, 0.f, 0.f, 0.f, 0.f, 0.f};
#pragma unroll
      for (int t = 0; t < KNEI; ++t) {
        const float w = Wl2[n][t];
        uint4 v = *(const uint4*)&Pl[Il2[n][t] * PALD + 8 * lane];
        a8[0] += w * bflo(v.x); a8[1] += w * bfhi(v.x);
        a8[2] += w * bflo(v.y); a8[3] += w * bfhi(v.y);
        a8[4] += w * bflo(v.z); a8[5] += w * bfhi(v.z);
        a8[6] += w * bflo(v.w); a8[7] += w * bfhi(v.w);
      }
      uint4 r;
      r.x = pack2bf(a8[0], a8[1]);
      r.y = pack2bf(a8[2], a8[3]);
      r.z = pack2bf(a8[4], a8[5]);
      r.w = pack2bf(a8[6], a8[7]);
      *(uint4*)(outp + (size_t)n * DIM + 8 * lane) = r;
    }
  }
}

// Combined GNN layer tail for BOTH branches in one launch (780 blocks,
// 64 rows/block): blocks [0,700) = V rows, [700,780) = P rows.
__global__ __launch_bounds__(512) void gemm_fused_kernel(
    const u16* __restrict__ Av, const u16* __restrict__ Ap,
    const u16* __restrict__ Wv, const u16* __restrict__ Wp,
    const float* __restrict__ bias_v, const float* __restrict__ bias_p,
    const float* __restrict__ sv, const float* __restrict__ sp,
    u16* __restrict__ XBv, u16* __restrict__ XBp,
    const u16* __restrict__ X0v, const u16* __restrict__ X0p) {
  const int bid = blockIdx.x;
  const bool isV = bid < NVB;
  const int row0 = (isV ? bid : bid - NVB) * 64;
  const u16* A = isV ? Av : Ap;
  const u16* W = isV ? Wv : Wp;
  const float* bias = isV ? bias_v : bias_p;
  const float* scale_ptr = isV ? sv : sp;
  u16* XB = isV ? XBv : XBp;
  const u16* X0B = isV ? X0v : X0p;
  const int tid = threadIdx.x, wave = tid >> 6, lane = tid & 63;
  __shared__ __align__(16) u16 smem[18432];  // Bs 32KB + As 4KB; U reuses Bs
  u16* Bs = smem;           // 512x32 u16
  u16* As = smem + 16384;   // 64x32 u16
  f32x4 acc[4][4];
#pragma unroll
  for (int m = 0; m < 4; ++m)
#pragma unroll
    for (int n = 0; n < 4; ++n) acc[m][n] = (f32x4){0.f, 0.f, 0.f, 0.f};
  const int rsrc = lane >> 2;        // 0..15
  const int ksrc = (lane & 3) * 8;   // 0,8,16,24
  for (int kk = 0; kk < DIM; kk += 32) {
#pragma unroll
    for (int q = 0; q < 4; ++q) {
      const int t = wave * 4 + q;  // 0..31 covers all 512 W rows
      gload16(W + (size_t)(t * 16 + rsrc) * DIM + kk + ksrc, Bs + t * 512);
    }
    if (wave < 4)
      gload16(A + (size_t)(row0 + wave * 16 + rsrc) * DIM + kk + ksrc,
              As + wave * 512);
    __syncthreads();
    s16x8 fa[4], fb[4];
#pragma unroll
    for (int m = 0; m < 4; ++m)
      fa[m] = ldfrag(&As[(m * 16 + (lane & 15)) * 32 + (lane >> 4) * 8]);
#pragma unroll
    for (int n = 0; n < 4; ++n)
      fb[n] = ldfrag(
          &Bs[(wave * 64 + n * 16 + (lane & 15)) * 32 + (lane >> 4) * 8]);
#pragma unroll
    for (int m = 0; m < 4; ++m)
#pragma unroll
      for (int n = 0; n < 4; ++n)
        acc[m][n] = __builtin_amdgcn_mfma_f32_16x16x32_bf16(fa[m], fb[n],
                                                            acc[m][n], 0, 0, 0);
    __syncthreads();
  }
  const float s = *scale_ptr;
  const int rq = lane >> 4, c_ = lane & 15;
  const int prow = tid >> 4, sub = tid & 15;   // epilogue thread map (32 rows)
  const int rq2 = ((prow >> 2) & 3) << 1;
#pragma unroll
  for (int half = 0; half < 2; ++half) {
    __syncthreads();
#pragma unroll
    for (int n = 0; n < 4; ++n) {
      const int col = wave * 64 + n * 16 + c_;
      const float bc = bias[col];
      const int cbase = col >> 3, wof = col & 7;
#pragma unroll
      for (int mm = 0; mm < 2; ++mm) {
        const int m = half * 2 + mm;
#pragma unroll
        for (int j = 0; j < 4; ++j) {
          const int lr = mm * 16 + rq * 4 + j;  // local row 0..31
          const int cS = cbase ^ (((lr >> 2) & 3) << 1);
          smem[lr * 512 + cS * 8 + wof] =
              pack1bf(s * tanh_fast(acc[m][n][j] + bc));
        }
      }
    }
    __syncthreads();
    const int grow = row0 + half * 32 + prow;
    const u16* xrow = XB + (size_t)grow * DIM;
    const u16* x0row = X0B + (size_t)grow * DIM;
    float ss = 0.f;
#pragma unroll
    for (int i = 0; i < 4; ++i) {
      const int c = sub + 16 * i;
      uint4 xb = *(const uint4*)(xrow + c * 8);
      uint4 x0 = *(const uint4*)(x0row + c * 8);
      uint4 uu = *(const uint4*)&smem[prow * 512 + (c ^ rq2) * 8];
      float t0 = 0.8f * (bflo(xb.x) + bflo(uu.x)) + 0.2f * bflo(x0.x);
      float t1 = 0.8f * (bfhi(xb.x) + bfhi(uu.x)) + 0.2f * bfhi(x0.x);
      float t2 = 0.8f * (bflo(xb.y) + bflo(uu.y)) + 0.2f * bflo(x0.y);
      float t3 = 0.8f * (bfhi(xb.y) + bfhi(uu.y)) + 0.2f * bfhi(x0.y);
      float t4 = 0.8f * (bflo(xb.z) + bflo(uu.z)) + 0.2f * bflo(x0.z);
      float t5 = 0.8f * (bfhi(xb.z) + bfhi(uu.z)) + 0.2f * bfhi(x0.z);
      float t6 = 0.8f * (bflo(xb.w) + bflo(uu.w)) + 0.2f * bflo(x0.w);
      float t7 = 0.8f * (bfhi(xb.w) + bfhi(uu.w)) + 0.2f * bfhi(x0.w);
      ss += t0 * t0 + t1 * t1 + t2 * t2 + t3 * t3 + t4 * t4 + t5 * t5 +
            t6 * t6 + t7 * t7;
      uint4 tp;
      tp.x = pack2bf(t0, t1); tp.y = pack2bf(t2, t3);
      tp.z = pack2bf(t4, t5); tp.w = pack2bf(t6, t7);
      *(uint4*)&smem[prow * 512 + (c ^ rq2) * 8] = tp;
    }
#pragma unroll
    for (int off = 8; off >= 1; off >>= 1) ss += __shfl_xor(ss, off, 16);
    const float inv = 1.f / fmaxf(sqrtf(ss), 1e-12f);
    u16* orow = XB + (size_t)grow * DIM;
#pragma unroll
    for (int i = 0; i < 4; ++i) {
      const int c = sub + 16 * i;
      uint4 tp = *(const uint4*)&smem[prow * 512 + (c ^ rq2) * 8];
      uint4 r;
      r.x = pack2bf(bflo(tp.x) * inv, bfhi(tp.x) * inv);
      r.y = pack2bf(bflo(tp.y) * inv, bfhi(tp.y) * inv);
      r.z = pack2bf(bflo(tp.z) * inv, bfhi(tp.z) * inv);
      r.w = pack2bf(bflo(tp.w) * inv, bfhi(tp.w) * inv);
      *(uint4*)(orow + c * 8) = r;
    }
  }
}

// Merged guidance tail, 2 blocks per episode (grid 512): sl = p>>8 picks the
// 96-row slice. v7 (best): double-buffered V (reads VC immutable, writes VN);
// step 2 widened to 7 waves: waves 0-5 own 16-row A-frags, wave 6 = Gram.
__global__ __launch_bounds__(512) void episode_post_kernel(
    const u16* __restrict__ VC, u16* __restrict__ VN,
    const u16* __restrict__ PB, const int* __restrict__ qy,
    const float* __restrict__ alpha_ptr, const float* __restrict__ beta_ptr,
    float* __restrict__ accum, int is_last) {
  const int p = blockIdx.x;
  const int b = p & 255, sl = p >> 8;  // 0..1
  const int tid = threadIdx.x, wave = tid >> 6, lane = tid & 63;
  __shared__ __align__(16) u16 palds[NWAYS * PALD];      // 20.8 KB
  __shared__ float SIMSl[96 * NWAYS];                    // 7.7 KB
  __shared__ float Gl[NWAYS][NWAYS + 1];                 // 1.7 KB
  __shared__ float red[16];
  const u16* Vb0 = VC + (size_t)b * NT * DIM;
  const float alpha = *alpha_ptr, oma = 1.f - alpha;
  const float beta = *beta_ptr, omb = 1.f - beta;
  const int row_lo = sl * 96;
  const int row_hi = (row_lo + 96 < NT) ? (row_lo + 96) : NT;
  // ---- step 1: Pa rows (vcpa) into palds (VC immutable -> deterministic) --
  for (int n = wave; n < NWAYS; n += 8) {
    const u16* base = Vb0 + (size_t)n * KSHOT * DIM;
    float a8[8] = {0.f, 0.f, 0.f, 0.f, 0.f, 0.f, 0.f, 0.f};
#pragma unroll
    for (int k = 0; k < KSHOT; ++k) {
      uint4 v = *(const uint4*)(base + (size_t)k * DIM + 8 * lane);
      a8[0] += bflo(v.x); a8[1] += bfhi(v.x);
      a8[2] += bflo(v.y); a8[3] += bfhi(v.y);
      a8[4] += bflo(v.z); a8[5] += bfhi(v.z);
      a8[6] += bflo(v.w); a8[7] += bfhi(v.w);
    }
    float ss = 0.f;
#pragma unroll
    for (int t = 0; t < 8; ++t) ss += a8[t] * a8[t];
    ss = waveReduceSum(ss);
    const float inv = 1.f / fmaxf(sqrtf(ss), 1e-12f);  // mean cancels in l2n
    {
      uint4 pp = *(const uint4*)(PB + ((size_t)b * NWAYS + n) * DIM + 8 * lane);
      a8[0] = alpha * bflo(pp.x) + oma * a8[0] * inv;
      a8[1] = alpha * bfhi(pp.x) + oma * a8[1] * inv;
      a8[2] = alpha * bflo(pp.y) + oma * a8[2] * inv;
      a8[3] = alpha * bfhi(pp.y) + oma * a8[3] * inv;
      a8[4] = alpha * bflo(pp.z) + oma * a8[4] * inv;
      a8[5] = alpha * bfhi(pp.z) + oma * a8[5] * inv;
      a8[6] = alpha * bflo(pp.w) + oma * a8[6] * inv;
      a8[7] = alpha * bfhi(pp.w) + oma * a8[7] * inv;
    }
    float s2 = 0.f;
#pragma unroll
    for (int t = 0; t < 8; ++t) s2 += a8[t] * a8[t];
    s2 = waveReduceSum(s2);
    const float inv2 = 1.f / fmaxf(sqrtf(s2), 1e-12f);
    uint4 r;
    r.x = pack2bf(a8[0] * inv2, a8[1] * inv2);
    r.y = pack2bf(a8[2] * inv2, a8[3] * inv2);
    r.z = pack2bf(a8[4] * inv2, a8[5] * inv2);
    r.w = pack2bf(a8[6] * inv2, a8[7] * inv2);
    *(uint4*)&palds[n * PALD + 8 * lane] = r;
  }
  __syncthreads();
  // ---- step 2: slice SIMS on waves 0-5 (16 rows each) + Gram on wave 6 ----
  const int part2 = lane >> 4, fr2 = lane & 15;
  if (wave < 6) {
    const int r0w = row_lo + wave * 16;
    f32x4 sacc[2];
    sacc[0] = (f32x4){0.f, 0.f, 0.f, 0.f};
    sacc[1] = (f32x4){0.f, 0.f, 0.f, 0.f};
    const int row = r0w + fr2;
    for (int kk = 0; kk < DIM; kk += 32) {
      s16x8 fa, fb[2];
      if (row < NT) {
        fa = __builtin_bit_cast(
            s16x8, *(const uint4*)(Vb0 + (size_t)row * DIM + kk + part2 * 8));
      } else {
        int pr = row - NT;
        if (pr > NWAYS - 1) pr = NWAYS - 1;
        fa = ldfrag(&palds[pr * PALD + kk + part2 * 8]);
      }
#pragma unroll
      for (int n = 0; n < 2; ++n)
        fb[n] = ldfrag(&palds[(n * 16 + fr2) * PALD + kk + part2 * 8]);
#pragma unroll
      for (int n = 0; n < 2; ++n)
        sacc[n] = __builtin_amdgcn_mfma_f32_16x16x32_bf16(fa, fb[n], sacc[n],
                                                          0, 0, 0);
    }
    const int r_ = (lane >> 4) * 4, c_ = lane & 15;
#pragma unroll
    for (int n = 0; n < 2; ++n)
#pragma unroll
      for (int j = 0; j < 4; ++j) {
        const int r = r0w + r_ + j, c = n * 16 + c_;
        if (c >= NWAYS) continue;
        if (r >= row_lo && r < row_hi)
          SIMSl[(r - row_lo) * NWAYS + c] = sacc[n][j];
        else if (r >= NT && r < NT + NWAYS)
          Gl[r - NT][c] = sacc[n][j];
      }
  } else if (wave == 6) {
    f32x4 sacc[2][2];
#pragma unroll
    for (int m = 0; m < 2; ++m)
#pragma unroll
      for (int n = 0; n < 2; ++n) sacc[m][n] = (f32x4){0.f, 0.f, 0.f, 0.f};
    for (int kk = 0; kk < DIM; kk += 32) {
      s16x8 fa[2], fb[2];
#pragma unroll
      for (int m = 0; m < 2; ++m) {
        int pr = m * 16 + fr2;
        if (pr > NWAYS - 1) pr = NWAYS - 1;
        fa[m] = ldfrag(&palds[pr * PALD + kk + part2 * 8]);
      }
#pragma unroll
      for (int n = 0; n < 2; ++n)
        fb[n] = ldfrag(&palds[(n * 16 + fr2) * PALD + kk + part2 * 8]);
#pragma unroll
      for (int m = 0; m < 2; ++m)
#pragma unroll
        for (int n = 0; n < 2; ++n)
          sacc[m][n] = __builtin_amdgcn_mfma_f32_16x16x32_bf16(
              fa[m], fb[n], sacc[m][n], 0, 0, 0);
    }
    const int r_ = (lane >> 4) * 4, c_ = lane & 15;
#pragma unroll
    for (int m = 0; m < 2; ++m)
#pragma unroll
      for (int n = 0; n < 2; ++n)
#pragma unroll
        for (int j = 0; j < 4; ++j) {
          const int r = m * 16 + r_ + j, c = n * 16 + c_;
          if (r < NWAYS && c < NWAYS) Gl[r][c] = sacc[m][n][j];
        }
  }
  __syncthreads();
  // ---- step 3: softmax + update (VC -> VN) + CE for query rows ----
  float ce_acc = 0.f, ac_acc = 0.f;
  if (!(is_last && sl == 0)) {
    const int rs = is_last ? ((row_lo > NKS ? row_lo : NKS) + wave)
                           : (row_lo + wave);
    for (int row = rs; row < row_hi; row += 8) {
      float s[NWAYS];
#pragma unroll
      for (int m = 0; m < NWAYS; ++m)
        s[m] = SIMSl[(row - row_lo) * NWAYS + m];  // broadcast
      float mx = s[0];
#pragma unroll
      for (int m = 1; m < NWAYS; ++m) mx = fmaxf(mx, s[m]);
      float e[NWAYS], wsum = 0.f, dN = 0.f;
#pragma unroll
      for (int m = 0; m < NWAYS; ++m) {
        e[m] = __expf((s[m] - mx) * TAU_INV);
        wsum += e[m];
        dN += e[m] * s[m];
      }
      const float cg = omb / wsum;
      const int ln = lane & 31;
      float sg = 0.f;
      if (ln < NWAYS) {
#pragma unroll
        for (int m = 0; m < NWAYS; ++m) sg += e[m] * Gl[m][ln];
      }
      float ege = (ln < NWAYS) ? e[ln] * sg : 0.f;
#pragma unroll
      for (int off = 16; off >= 1; off >>= 1) ege += __shfl_xor(ege, off, 32);
      const float nn2 = beta * beta + 2.f * beta * cg * dN + cg * cg * ege;
      const float inv = 1.f / fmaxf(sqrtf(nn2), 1e-12f);
      if (!is_last) {
        const u16* vrow = VC + ((size_t)b * NT + row) * DIM;
        uint4 v4 = *(const uint4*)(vrow + 8 * lane);
        float t0 = 0.f, t1 = 0.f, t2 = 0.f, t3 = 0.f;
        float t4 = 0.f, t5 = 0.f, t6 = 0.f, t7 = 0.f;
#pragma unroll
        for (int m = 0; m < NWAYS; ++m) {
          uint4 pp = *(const uint4*)&palds[m * PALD + 8 * lane];
          t0 += e[m] * bflo(pp.x); t1 += e[m] * bfhi(pp.x);
          t2 += e[m] * bflo(pp.y); t3 += e[m] * bfhi(pp.y);
          t4 += e[m] * bflo(pp.z); t5 += e[m] * bfhi(pp.z);
          t6 += e[m] * bflo(pp.w); t7 += e[m] * bfhi(pp.w);
        }
        uint4 r;
        r.x = pack2bf((beta * bflo(v4.x) + cg * t0) * inv,
                      (beta * bfhi(v4.x) + cg * t1) * inv);
        r.y = pack2bf((beta * bflo(v4.y) + cg * t2) * inv,
                      (beta * bfhi(v4.y) + cg * t3) * inv);
        r.z = pack2bf((beta * bflo(v4.z) + cg * t4) * inv,
                      (beta * bfhi(v4.z) + cg * t5) * inv);
        r.w = pack2bf((beta * bflo(v4.w) + cg * t6) * inv,
                      (beta * bfhi(v4.w) + cg * t7) * inv);
        *(uint4*)(VN + ((size_t)b * NT + row) * DIM + 8 * lane) = r;
      }
      if (row >= NKS) {
        float l = (ln < NWAYS)
                      ? LOGIT_SCALE * inv * (beta * s[ln] + cg * sg)
                      : -1e30f;
        float bv = l;
        int bi = ln;
#pragma unroll
        for (int off = 16; off >= 1; off >>= 1) {
          float ov = __shfl_xor(bv, off, 32);
          int oi = __shfl_xor(bi, off, 32);
          if (ov > bv || (ov == bv && oi < bi)) { bv = ov; bi = oi; }
        }
        float se = (ln < NWAYS) ? __expf(l - bv) : 0.f;
#pragma unroll
        for (int off = 16; off >= 1; off >>= 1) se += __shfl_xor(se, off, 32);
        const int yt = qy[b * NQ + (row - NKS)];
        const float ly = __shfl(l, yt, 32);
        if (lane == 0) {
          ce_acc += bv + __logf(se) - ly;
          ac_acc += (bi == yt) ? 1.f : 0.f;
        }
      }
    }
  }
  if (lane == 0) {
    red[wave] = ce_acc;
    red[8 + wave] = ac_acc;
  }
  __syncthreads();
  if (tid == 0 && sl == 1) {
    float ce = 0.f, ac = 0.f;
#pragma unroll
    for (int w8 = 0; w8 < 8; ++w8) {
      ce += red[w8];
      ac += red[8 + w8];
    }
    atomicAdd(&accum[0], ce);
    if (is_last) atomicAdd(&accum[1], ac);
  } else if (tid == 0 && sl == 0 && !is_last) {
    float ce = 0.f;
#pragma unroll
    for (int w8 = 0; w8 < 8; ++w8) ce += red[w8];
    atomicAdd(&accum[0], ce);
  }
}

__global__ void finalize_kernel(const float* __restrict__ acc,
                                float* __restrict__ out) {
  out[0] = acc[0] / (float)(NLAYERS * B_EP * NQ);
  out[1] = acc[1] / (float)(B_EP * NQ);
}

extern "C" void kernel_launch(void* const* d_in, const int* in_sizes, int n_in,
                              void* d_out, int out_size, void* d_ws,
                              size_t ws_size, hipStream_t stream) {
  const float* V_feat = (const float*)d_in[0];
  const float* P_feat = (const float*)d_in[1];
  const int* query_y = (const int*)d_in[2];
  const float* igb_W = (const float*)d_in[3];
  const float* igb_b = (const float*)d_in[4];
  const float* igb_s = (const float*)d_in[5];
  const float* pgb_W = (const float*)d_in[6];
  const float* pgb_b = (const float*)d_in[7];
  const float* pgb_s = (const float*)d_in[8];
  const float* alpha = (const float*)d_in[9];
  const float* beta = (const float*)d_in[10];
  float* out = (float*)d_out;

  float* ws = (float*)d_ws;
  const size_t vsz = (size_t)B_EP * NT * DIM;       // 22,937,600
  const size_t psz = (size_t)B_EP * NWAYS * DIM;    // 2,621,440
  const size_t wsz = (size_t)NLAYERS * DIM * DIM;   // 1,048,576
  float* ACC = ws;
  u16* VB = (u16*)(ws + 16);
  u16* V0B = VB + vsz;
  u16* MSGB = V0B + vsz;
  u16* PB = MSGB + vsz;
  u16* P0B = PB + psz;
  u16* PMSGB = P0B + psz;
  u16* WB = PMSGB + psz;
  u16* WPB = WB + wsz;

  init_accum_kernel<<<1, 64, 0, stream>>>(ACC);
  l2n_init_kernel<<<B_EP * NT, 64, 0, stream>>>(V_feat, VB, V0B);
  l2n_init_kernel<<<B_EP * NWAYS, 64, 0, stream>>>(P_feat, PB, P0B);
  {
    const int n8 = (int)(wsz / 8);
    const int nb1 = (n8 + 255) / 256;
    cvt_bf16_kernel<<<2 * nb1, 256, 0, stream>>>(igb_W, pgb_W, WB, n8);
  }

  for (int i = 0; i < NLAYERS; ++i) {
    u16* Vc = (i & 1) ? MSGB : VB;   // current V
    u16* Mn = (i & 1) ? VB : MSGB;   // message buffer, then V_next
    graph_front_kernel<<<4 * B_EP, 256, 0, stream>>>(Vc, PB, Mn, PMSGB);
    gemm_fused_kernel<<<NVB + B_EP * NWAYS / 64, 512, 0, stream>>>(
        Mn, PMSGB, WB + (size_t)i * DIM * DIM, WPB + (size_t)i * DIM * DIM,
        igb_b + (size_t)i * DIM, pgb_b + (size_t)i * DIM, igb_s + i, pgb_s + i,
        Vc, PB, V0B, P0B);
    episode_post_kernel<<<2 * B_EP, 512, 0, stream>>>(
        Vc, Mn, PB, query_y, alpha, beta, ACC, (i == NLAYERS - 1) ? 1 : 0);
  }
  finalize_kernel<<<1, 1, 0, stream>>>(ACC, out);
}